// Round 1
// baseline (37331.601 us; speedup 1.0000x reference)
//
#include <hip/hip_runtime.h>
#include <hip/hip_bf16.h>

// Problem constants (match reference)
#define N_ATOMS 100000
#define N_EDGES 1600000
#define D       128   // D_ATOM
#define DE      100   // D_EDGE
#define DSPH    9     // D_SPH
#define H2      64    // hidden 2

typedef __hip_bfloat16 bf16;

__device__ __forceinline__ float blo(unsigned int u) {
  union { unsigned int i; float f; } v; v.i = u << 16; return v.f;
}
__device__ __forceinline__ float bhi(unsigned int u) {
  union { unsigned int i; float f; } v; v.i = u & 0xffff0000u; return v.f;
}
__device__ __forceinline__ float fsig(float x) {
  return __builtin_amdgcn_rcpf(1.0f + __expf(-x));
}
__device__ __forceinline__ float fsilu(float x) { return x * fsig(x); }

// ---------------------------------------------------------------------------
// Kernel 1: per-atom partial layer-1 products.
// PA  = atom @ W1[0:128,:]   PB  = atom @ W1[128:256,:]
// PGA = atom @ G1[0:128,:]   PGB = atom @ G1[128:256,:]     (all bf16)
// Block: 256 thr -> 16x16 (atom-group x col-group), 32 atoms/block.
// ---------------------------------------------------------------------------
__global__ __launch_bounds__(256) void k_tables(
    const float* __restrict__ atom, const float* __restrict__ W1,
    const float* __restrict__ G1,
    bf16* __restrict__ PA, bf16* __restrict__ PB,
    bf16* __restrict__ PGA, bf16* __restrict__ PGB)
{
  __shared__ __align__(16) float at[32][132];   // pad 132: (4a+k)%32 spreads banks
  const int tid = threadIdx.x;
  const size_t abase = (size_t)blockIdx.x * 32;

  for (int i = tid; i < 1024; i += 256) {       // 32 rows x 32 float4
    int a = i >> 5, c = i & 31;
    *(float4*)&at[a][c * 4] = ((const float4*)(atom + (abase + a) * D))[c];
  }
  __syncthreads();

  const int tj = tid & 15;   // cols j = tj*8 .. tj*8+7
  const int ta = tid >> 4;   // atoms ta*2, ta*2+1

  for (int t = 0; t < 4; ++t) {
    const float* W = ((t < 2) ? W1 : G1) + (t & 1) * (D * D);
    bf16* P = (t == 0) ? PA : (t == 1) ? PB : (t == 2) ? PGA : PGB;
    float acc0[8], acc1[8];
#pragma unroll
    for (int c = 0; c < 8; ++c) { acc0[c] = 0.f; acc1[c] = 0.f; }
#pragma unroll 4
    for (int k = 0; k < D; ++k) {
      const float a0 = at[ta * 2][k];
      const float a1 = at[ta * 2 + 1][k];
      const float4 w0 = *(const float4*)&W[k * D + tj * 8];
      const float4 w1 = *(const float4*)&W[k * D + tj * 8 + 4];
      acc0[0] = fmaf(a0, w0.x, acc0[0]); acc1[0] = fmaf(a1, w0.x, acc1[0]);
      acc0[1] = fmaf(a0, w0.y, acc0[1]); acc1[1] = fmaf(a1, w0.y, acc1[1]);
      acc0[2] = fmaf(a0, w0.z, acc0[2]); acc1[2] = fmaf(a1, w0.z, acc1[2]);
      acc0[3] = fmaf(a0, w0.w, acc0[3]); acc1[3] = fmaf(a1, w0.w, acc1[3]);
      acc0[4] = fmaf(a0, w1.x, acc0[4]); acc1[4] = fmaf(a1, w1.x, acc1[4]);
      acc0[5] = fmaf(a0, w1.y, acc0[5]); acc1[5] = fmaf(a1, w1.y, acc1[5]);
      acc0[6] = fmaf(a0, w1.z, acc0[6]); acc1[6] = fmaf(a1, w1.z, acc1[6]);
      acc0[7] = fmaf(a0, w1.w, acc0[7]); acc1[7] = fmaf(a1, w1.w, acc1[7]);
    }
    bf16* p0 = P + (abase + ta * 2) * D + tj * 8;
    bf16* p1 = p0 + D;
#pragma unroll
    for (int c = 0; c < 8; ++c) {
      p0[c] = __float2bfloat16(acc0[c]);
      p1[c] = __float2bfloat16(acc1[c]);
    }
  }
}

// ---------------------------------------------------------------------------
// Kernel 2: out = atom_attr  (agg accumulates on top via atomics)
// ---------------------------------------------------------------------------
__global__ void k_init(const float4* __restrict__ a, float4* __restrict__ o, int n4) {
  int i = blockIdx.x * blockDim.x + threadIdx.x;
  const int st = gridDim.x * blockDim.x;
  for (; i < n4; i += st) o[i] = a[i];
}

// ---------------------------------------------------------------------------
// Kernel 3: per-edge gated MLP + scatter-add. 1024 thr = 16 waves, wave/edge.
// ---------------------------------------------------------------------------
#define WPB 16
__global__ __launch_bounds__(1024, 4) void k_edges(
    const float* __restrict__ ea,   // edge_attr [E,100]
    const float* __restrict__ eap,  // edge_attr_prime [E,9]
    const int*  __restrict__ ei,    // edge_index [2,E]
    const bf16* __restrict__ PA, const bf16* __restrict__ PB,
    const bf16* __restrict__ PGA, const bf16* __restrict__ PGB,
    const float* __restrict__ W1, const float* __restrict__ G1,
    const float* __restrict__ b1, const float* __restrict__ g1,
    const float* __restrict__ W2, const float* __restrict__ b2,
    const float* __restrict__ W3, const float* __restrict__ b3,
    const float* __restrict__ G2, const float* __restrict__ g2,
    const float* __restrict__ G3, const float* __restrict__ g3,
    const float* __restrict__ We, const float* __restrict__ be,
    float* __restrict__ out)
{
  // Transposed bf16 weight tiles; row pads keep 16B alignment for uint4 reads.
  __shared__ __align__(16) unsigned short W2T[64][136];   // W2T[j][k] = W2[k][j]
  __shared__ __align__(16) unsigned short G2T[64][136];
  __shared__ __align__(16) unsigned short W3T[128][72];   // W3T[j][k] = W3[k][j]
  __shared__ __align__(16) unsigned short G3T[128][72];
  __shared__ float W1cT[128][13];  // W1 rows 256..264 transposed (odd pad: bank-spread)
  __shared__ float G1cT[128][13];
  __shared__ float b1s[128], g1s[128], b2s[64], g2s[64], b3s[128], g3s[128];
  __shared__ float We_s[100];
  __shared__ __align__(16) float h1m[WPB][128], h1g[WPB][128];
  __shared__ __align__(16) float h2m[WPB][64],  h2g[WPB][64];

  const int tid = threadIdx.x;
  // ---- stage weights (bf16) ----
  for (int i = tid; i < 64 * 128; i += 1024) {
    int j = i >> 7, k = i & 127;
    bf16 w = __float2bfloat16(W2[k * 64 + j]);
    bf16 g = __float2bfloat16(G2[k * 64 + j]);
    W2T[j][k] = *(unsigned short*)&w;
    G2T[j][k] = *(unsigned short*)&g;
  }
  for (int i = tid; i < 128 * 64; i += 1024) {
    int j = i >> 6, k = i & 63;
    bf16 w = __float2bfloat16(W3[k * 128 + j]);
    bf16 g = __float2bfloat16(G3[k * 128 + j]);
    W3T[j][k] = *(unsigned short*)&w;
    G3T[j][k] = *(unsigned short*)&g;
  }
  for (int i = tid; i < 128 * 9; i += 1024) {
    int k = i / 128, j = i % 128;
    W1cT[j][k] = W1[(256 + k) * 128 + j];
    G1cT[j][k] = G1[(256 + k) * 128 + j];
  }
  if (tid < 128) { b1s[tid] = b1[tid]; g1s[tid] = g1[tid]; b3s[tid] = b3[tid]; g3s[tid] = g3[tid]; }
  if (tid >= 128 && tid < 192) { b2s[tid - 128] = b2[tid - 128]; g2s[tid - 128] = g2[tid - 128]; }
  if (tid >= 192 && tid < 292) We_s[tid - 192] = We[tid - 192];
  __syncthreads();

  const int lane = tid & 63;
  const int wv   = tid >> 6;
  const long wgid = (long)blockIdx.x * WPB + wv;
  const long nW   = (long)gridDim.x * WPB;
  const int iters = (int)((N_EDGES + nW - 1) / nW);   // uniform across block
  const float beV = be[0];

  for (int it = 0; it < iters; ++it) {
    const long e = wgid + (long)it * nW;
    const bool act = (e < N_EDGES);
    int srcA = 0, dstA = 0;
    float sc = 0.f;

    if (act) {
      srcA = ei[e];
      dstA = ei[N_EDGES + e];
      // per-edge scalar: edge_attr @ We + be (butterfly reduce over wave)
      const float* ear = ea + (size_t)e * DE;
      float s = ear[lane] * We_s[lane];
      if (lane < DE - 64) s += ear[64 + lane] * We_s[64 + lane];
#pragma unroll
      for (int o = 32; o; o >>= 1) s += __shfl_xor(s, o);
      sc = s + beV;

      // layer 1: gathered precomputed partials + sph term
      const float* sp = eap + (size_t)e * DSPH;
      float sph[9];
#pragma unroll
      for (int k = 0; k < 9; ++k) sph[k] = sp[k];
#pragma unroll
      for (int hh = 0; hh < 2; ++hh) {
        const int j = lane + 64 * hh;
        float zm = __bfloat162float(PA[(size_t)srcA * D + j]) +
                   __bfloat162float(PB[(size_t)dstA * D + j]) + b1s[j];
        float zg = __bfloat162float(PGA[(size_t)srcA * D + j]) +
                   __bfloat162float(PGB[(size_t)dstA * D + j]) + g1s[j];
#pragma unroll
        for (int k = 0; k < 9; ++k) {
          zm = fmaf(sph[k], W1cT[j][k], zm);
          zg = fmaf(sph[k], G1cT[j][k], zg);
        }
        h1m[wv][j] = fsilu(zm);
        h1g[wv][j] = fsilu(zg);
      }
    }
    __syncthreads();

    if (act) {
      // layer 2: 128 -> 64, lane j owns output col j
      const int j = lane;
      float am = b2s[j], ag = g2s[j];
      const uint4* wrow = (const uint4*)&W2T[j][0];
      const uint4* grow = (const uint4*)&G2T[j][0];
      const float4* hm = (const float4*)&h1m[wv][0];
      const float4* hg = (const float4*)&h1g[wv][0];
#pragma unroll
      for (int c = 0; c < 16; ++c) {
        const uint4 w = wrow[c], g = grow[c];
        const float4 m0 = hm[2 * c], m1 = hm[2 * c + 1];
        const float4 q0 = hg[2 * c], q1 = hg[2 * c + 1];
        am = fmaf(m0.x, blo(w.x), am); am = fmaf(m0.y, bhi(w.x), am);
        am = fmaf(m0.z, blo(w.y), am); am = fmaf(m0.w, bhi(w.y), am);
        am = fmaf(m1.x, blo(w.z), am); am = fmaf(m1.y, bhi(w.z), am);
        am = fmaf(m1.z, blo(w.w), am); am = fmaf(m1.w, bhi(w.w), am);
        ag = fmaf(q0.x, blo(g.x), ag); ag = fmaf(q0.y, bhi(g.x), ag);
        ag = fmaf(q0.z, blo(g.y), ag); ag = fmaf(q0.w, bhi(g.y), ag);
        ag = fmaf(q1.x, blo(g.z), ag); ag = fmaf(q1.y, bhi(g.z), ag);
        ag = fmaf(q1.z, blo(g.w), ag); ag = fmaf(q1.w, bhi(g.w), ag);
      }
      h2m[wv][j] = fsilu(am);
      h2g[wv][j] = fsilu(ag);
    }
    __syncthreads();

    if (act) {
      // layer 3: 64 -> 128, + gate sigmoid + scalar + scatter
#pragma unroll
      for (int hh = 0; hh < 2; ++hh) {
        const int j = lane + 64 * hh;
        float am = b3s[j], ag = g3s[j];
        const uint4* wrow = (const uint4*)&W3T[j][0];
        const uint4* grow = (const uint4*)&G3T[j][0];
        const float4* hm = (const float4*)&h2m[wv][0];
        const float4* hg = (const float4*)&h2g[wv][0];
#pragma unroll
        for (int c = 0; c < 8; ++c) {
          const uint4 w = wrow[c], g = grow[c];
          const float4 m0 = hm[2 * c], m1 = hm[2 * c + 1];
          const float4 q0 = hg[2 * c], q1 = hg[2 * c + 1];
          am = fmaf(m0.x, blo(w.x), am); am = fmaf(m0.y, bhi(w.x), am);
          am = fmaf(m0.z, blo(w.y), am); am = fmaf(m0.w, bhi(w.y), am);
          am = fmaf(m1.x, blo(w.z), am); am = fmaf(m1.y, bhi(w.z), am);
          am = fmaf(m1.z, blo(w.w), am); am = fmaf(m1.w, bhi(w.w), am);
          ag = fmaf(q0.x, blo(g.x), ag); ag = fmaf(q0.y, bhi(g.x), ag);
          ag = fmaf(q0.z, blo(g.y), ag); ag = fmaf(q0.w, bhi(g.y), ag);
          ag = fmaf(q1.x, blo(g.z), ag); ag = fmaf(q1.y, bhi(g.z), ag);
          ag = fmaf(q1.z, blo(g.w), ag); ag = fmaf(q1.w, bhi(g.w), ag);
        }
        const float msg = fsilu(am) * fsig(ag) * sc;
        atomicAdd(out + (size_t)dstA * D + j, msg);
      }
    }
    __syncthreads();
  }
}

// ---------------------------------------------------------------------------
extern "C" void kernel_launch(void* const* d_in, const int* in_sizes, int n_in,
                              void* d_out, int out_size, void* d_ws, size_t ws_size,
                              hipStream_t stream) {
  const float* atom = (const float*)d_in[0];
  const float* ea   = (const float*)d_in[1];
  const float* eap  = (const float*)d_in[2];
  const int*   ei   = (const int*)d_in[3];
  // d_in[4] = num_atoms (compile-time constant here)
  const float* W1 = (const float*)d_in[5];
  const float* b1 = (const float*)d_in[6];
  const float* W2 = (const float*)d_in[7];
  const float* b2 = (const float*)d_in[8];
  const float* W3 = (const float*)d_in[9];
  const float* b3 = (const float*)d_in[10];
  const float* G1 = (const float*)d_in[11];
  const float* g1 = (const float*)d_in[12];
  const float* G2 = (const float*)d_in[13];
  const float* g2 = (const float*)d_in[14];
  const float* G3 = (const float*)d_in[15];
  const float* g3 = (const float*)d_in[16];
  const float* We = (const float*)d_in[17];
  const float* be = (const float*)d_in[18];
  float* out = (float*)d_out;

  // Workspace: 4 bf16 tables of [N_ATOMS, 128] = 102.4 MB total (assumed <= ws_size).
  bf16* PA  = (bf16*)d_ws;
  bf16* PB  = PA + (size_t)N_ATOMS * D;
  bf16* PGA = PB + (size_t)N_ATOMS * D;
  bf16* PGB = PGA + (size_t)N_ATOMS * D;

  hipLaunchKernelGGL(k_tables, dim3(N_ATOMS / 32), dim3(256), 0, stream,
                     atom, W1, G1, PA, PB, PGA, PGB);
  hipLaunchKernelGGL(k_init, dim3(2048), dim3(256), 0, stream,
                     (const float4*)atom, (float4*)out, N_ATOMS * D / 4);
  hipLaunchKernelGGL(k_edges, dim3(256), dim3(1024), 0, stream,
                     ea, eap, ei, PA, PB, PGA, PGB, W1, G1, b1, g1,
                     W2, b2, W3, b3, G2, g2, G3, g3, We, be, out);
}

// Round 2
// 5746.957 us; speedup vs baseline: 6.4959x; 6.4959x over previous
//
#include <hip/hip_runtime.h>
#include <hip/hip_bf16.h>

#define N_ATOMS 100000
#define N_EDGES 1600000
#define D       128
#define DE      100
#define DSPH    9

typedef __hip_bfloat16 bf16;

__device__ __forceinline__ float blo(unsigned int u) {
  union { unsigned int i; float f; } v; v.i = u << 16; return v.f;
}
__device__ __forceinline__ float bhi(unsigned int u) {
  union { unsigned int i; float f; } v; v.i = u & 0xffff0000u; return v.f;
}
__device__ __forceinline__ float fsig(float x) {
  return __builtin_amdgcn_rcpf(1.0f + __expf(-x));
}
__device__ __forceinline__ float fsilu(float x) { return x * fsig(x); }

// wave-internal LDS ordering: all prior ds ops complete; compiler may not
// reorder memory ops across it ("memory" clobber). LDS ops are in-order per wave.
#define WSYNC() asm volatile("s_waitcnt lgkmcnt(0)" ::: "memory")

// ---------------------------------------------------------------------------
// Kernel 1: per-atom partial layer-1 products (bf16 tables).
// ---------------------------------------------------------------------------
__global__ __launch_bounds__(256) void k_tables(
    const float* __restrict__ atom, const float* __restrict__ W1,
    const float* __restrict__ G1,
    bf16* __restrict__ PA, bf16* __restrict__ PB,
    bf16* __restrict__ PGA, bf16* __restrict__ PGB)
{
  __shared__ __align__(16) float at[32][132];
  const int tid = threadIdx.x;
  const size_t abase = (size_t)blockIdx.x * 32;

  for (int i = tid; i < 1024; i += 256) {
    int a = i >> 5, c = i & 31;
    *(float4*)&at[a][c * 4] = ((const float4*)(atom + (abase + a) * D))[c];
  }
  __syncthreads();

  const int tj = tid & 15;
  const int ta = tid >> 4;

  for (int t = 0; t < 4; ++t) {
    const float* W = ((t < 2) ? W1 : G1) + (t & 1) * (D * D);
    bf16* P = (t == 0) ? PA : (t == 1) ? PB : (t == 2) ? PGA : PGB;
    float acc0[8], acc1[8];
#pragma unroll
    for (int c = 0; c < 8; ++c) { acc0[c] = 0.f; acc1[c] = 0.f; }
#pragma unroll 4
    for (int k = 0; k < D; ++k) {
      const float a0 = at[ta * 2][k];
      const float a1 = at[ta * 2 + 1][k];
      const float4 w0 = *(const float4*)&W[k * D + tj * 8];
      const float4 w1 = *(const float4*)&W[k * D + tj * 8 + 4];
      acc0[0] = fmaf(a0, w0.x, acc0[0]); acc1[0] = fmaf(a1, w0.x, acc1[0]);
      acc0[1] = fmaf(a0, w0.y, acc0[1]); acc1[1] = fmaf(a1, w0.y, acc1[1]);
      acc0[2] = fmaf(a0, w0.z, acc0[2]); acc1[2] = fmaf(a1, w0.z, acc1[2]);
      acc0[3] = fmaf(a0, w0.w, acc0[3]); acc1[3] = fmaf(a1, w0.w, acc1[3]);
      acc0[4] = fmaf(a0, w1.x, acc0[4]); acc1[4] = fmaf(a1, w1.x, acc1[4]);
      acc0[5] = fmaf(a0, w1.y, acc0[5]); acc1[5] = fmaf(a1, w1.y, acc1[5]);
      acc0[6] = fmaf(a0, w1.z, acc0[6]); acc1[6] = fmaf(a1, w1.z, acc1[6]);
      acc0[7] = fmaf(a0, w1.w, acc0[7]); acc1[7] = fmaf(a1, w1.w, acc1[7]);
    }
    bf16* p0 = P + (abase + ta * 2) * D + tj * 8;
    bf16* p1 = p0 + D;
#pragma unroll
    for (int c = 0; c < 8; ++c) {
      p0[c] = __float2bfloat16(acc0[c]);
      p1[c] = __float2bfloat16(acc1[c]);
    }
  }
}

// ---------------------------------------------------------------------------
// CSR build: histogram -> scan -> scatter
// ---------------------------------------------------------------------------
__global__ __launch_bounds__(256) void k_hist(const int* __restrict__ ei,
                                              int* __restrict__ counts) {
  int e = blockIdx.x * 256 + threadIdx.x;
  if (e < N_EDGES) atomicAdd(&counts[ei[N_EDGES + e]], 1);
}

__global__ __launch_bounds__(1024) void k_scan(const int* __restrict__ counts,
                                               int* __restrict__ roff) {
  __shared__ int ssum[1024];
  const int tid = threadIdx.x;
  const int CH = (N_ATOMS + 1023) / 1024;  // 98
  const int base = tid * CH;
  int s = 0;
  for (int k = 0; k < CH; ++k) {
    int idx = base + k;
    if (idx < N_ATOMS) s += counts[idx];
  }
  ssum[tid] = s;
  __syncthreads();
  for (int off = 1; off < 1024; off <<= 1) {
    int v = 0;
    if (tid >= off) v = ssum[tid - off];
    __syncthreads();
    if (tid >= off) ssum[tid] += v;
    __syncthreads();
  }
  s = (tid == 0) ? 0 : ssum[tid - 1];
  for (int k = 0; k < CH; ++k) {
    int idx = base + k;
    if (idx < N_ATOMS) { roff[idx] = s; s += counts[idx]; }
  }
  if (tid == 1023) roff[N_ATOMS] = s;
}

__global__ __launch_bounds__(256) void k_scatter(const int* __restrict__ ei,
                                                 const int* __restrict__ roff,
                                                 int* __restrict__ cursor,
                                                 int* __restrict__ perm) {
  int e = blockIdx.x * 256 + threadIdx.x;
  if (e < N_EDGES) {
    int d = ei[N_EDGES + e];
    int p = atomicAdd(&cursor[d], 1);
    perm[roff[d] + p] = e;
  }
}

// ---------------------------------------------------------------------------
// Kernel 5: wave-per-atom gated MLP + local accumulate. No atomics.
// 1024 thr = 16 waves; wave wv owns atom blockIdx.x*16+wv.
// Lane owns output columns (2*lane, 2*lane+1) for layers 1 & 3; col lane for layer 2.
// ---------------------------------------------------------------------------
#define WPB 16
__global__ __launch_bounds__(1024, 1) void k_atoms(
    const float* __restrict__ atom,
    const float* __restrict__ ea, const float* __restrict__ eap,
    const int*  __restrict__ ei,
    const int*  __restrict__ roff, const int* __restrict__ perm,
    const bf16* __restrict__ PA, const bf16* __restrict__ PB,
    const bf16* __restrict__ PGA, const bf16* __restrict__ PGB,
    const float* __restrict__ W1, const float* __restrict__ G1,
    const float* __restrict__ b1, const float* __restrict__ g1,
    const float* __restrict__ W2, const float* __restrict__ b2,
    const float* __restrict__ W3, const float* __restrict__ b3,
    const float* __restrict__ G2, const float* __restrict__ g2,
    const float* __restrict__ G3, const float* __restrict__ g3,
    const float* __restrict__ We, const float* __restrict__ be,
    float* __restrict__ out)
{
  __shared__ __align__(16) unsigned short W2T[64][136];  // [col j][k] stride 17 quads
  __shared__ __align__(16) unsigned short G2T[64][136];
  __shared__ __align__(16) unsigned short W3T[128][72];  // [col j][k] stride 9 quads
  __shared__ __align__(16) unsigned short G3T[128][72];
  __shared__ __align__(16) float W1c[9][128];            // natural layout of rows 256..264
  __shared__ __align__(16) float G1c[9][128];
  __shared__ float b1s[128], g1s[128], b2s[64], g2s[64], b3s[128], g3s[128];
  __shared__ float We_s[100];
  __shared__ __align__(16) float h1m[WPB][128], h1g[WPB][128];
  __shared__ __align__(16) float h2m[WPB][64],  h2g[WPB][64];

  const int tid = threadIdx.x;
  for (int i = tid; i < 64 * 128; i += 1024) {
    int j = i >> 7, k = i & 127;
    bf16 w = __float2bfloat16(W2[k * 64 + j]);
    bf16 g = __float2bfloat16(G2[k * 64 + j]);
    W2T[j][k] = *(unsigned short*)&w;
    G2T[j][k] = *(unsigned short*)&g;
  }
  for (int i = tid; i < 128 * 64; i += 1024) {
    int j = i >> 6, k = i & 63;
    bf16 w = __float2bfloat16(W3[k * 128 + j]);
    bf16 g = __float2bfloat16(G3[k * 128 + j]);
    W3T[j][k] = *(unsigned short*)&w;
    G3T[j][k] = *(unsigned short*)&g;
  }
  for (int i = tid; i < 9 * 128; i += 1024) {
    W1c[0][i] = W1[256 * 128 + i];   // contiguous block rows 256..264
    G1c[0][i] = G1[256 * 128 + i];
  }
  if (tid < 128) { b1s[tid] = b1[tid]; g1s[tid] = g1[tid]; b3s[tid] = b3[tid]; g3s[tid] = g3[tid]; }
  if (tid >= 128 && tid < 192) { b2s[tid - 128] = b2[tid - 128]; g2s[tid - 128] = g2[tid - 128]; }
  if (tid >= 192 && tid < 292) We_s[tid - 192] = We[tid - 192];
  __syncthreads();   // only block-wide barrier

  const int lane = tid & 63;
  const int wv   = tid >> 6;
  const int a    = blockIdx.x * WPB + wv;
  if (a >= N_ATOMS) return;
  const int j0 = 2 * lane;
  const float beV = be[0];

  // output accumulators initialized with atom_attr (residual)
  float2 accA = *(const float2*)(atom + (size_t)a * D + j0);
  // dst-side layer-1 partials, hoisted
  const unsigned pbu  = *(const unsigned*)(PB  + (size_t)a * D + j0);
  const unsigned pgbu = *(const unsigned*)(PGB + (size_t)a * D + j0);
  const float pbm0 = blo(pbu),  pbm1 = bhi(pbu);
  const float pgb0 = blo(pgbu), pgb1 = bhi(pgbu);
  const float b1a = b1s[j0], b1b = b1s[j0 + 1];
  const float g1a = g1s[j0], g1b = g1s[j0 + 1];

  const int r0 = roff[a], r1 = roff[a + 1];
  for (int i = r0; i < r1; ++i) {
    const int e   = perm[i];              // wave-uniform
    const int src = ei[e];
    // per-edge scalar
    const float* ear = ea + (size_t)e * DE;
    float s = ear[lane] * We_s[lane];
    if (lane < DE - 64) s += ear[64 + lane] * We_s[64 + lane];
#pragma unroll
    for (int o = 32; o; o >>= 1) s += __shfl_xor(s, o);
    const float sc = s + beV;
    // sph (wave-uniform broadcast loads)
    const float* sp = eap + (size_t)e * DSPH;
    float sph[9];
#pragma unroll
    for (int k = 0; k < 9; ++k) sph[k] = sp[k];

    // ---- layer 1 ----
    const unsigned pau  = *(const unsigned*)(PA  + (size_t)src * D + j0);
    const unsigned pgau = *(const unsigned*)(PGA + (size_t)src * D + j0);
    float zm0 = blo(pau)  + pbm0 + b1a;
    float zm1 = bhi(pau)  + pbm1 + b1b;
    float zg0 = blo(pgau) + pgb0 + g1a;
    float zg1 = bhi(pgau) + pgb1 + g1b;
#pragma unroll
    for (int k = 0; k < 9; ++k) {
      const float2 wm = *(const float2*)&W1c[k][j0];
      const float2 wg = *(const float2*)&G1c[k][j0];
      zm0 = fmaf(sph[k], wm.x, zm0); zm1 = fmaf(sph[k], wm.y, zm1);
      zg0 = fmaf(sph[k], wg.x, zg0); zg1 = fmaf(sph[k], wg.y, zg1);
    }
    *(float2*)&h1m[wv][j0] = make_float2(fsilu(zm0), fsilu(zm1));
    *(float2*)&h1g[wv][j0] = make_float2(fsilu(zg0), fsilu(zg1));
    WSYNC();

    // ---- layer 2: col j = lane ----
    {
      float am = b2s[lane], ag = g2s[lane];
      const uint4* wrow = (const uint4*)&W2T[lane][0];
      const uint4* grow = (const uint4*)&G2T[lane][0];
      const float4* hm = (const float4*)&h1m[wv][0];
      const float4* hg = (const float4*)&h1g[wv][0];
#pragma unroll
      for (int c = 0; c < 16; ++c) {
        const uint4 w = wrow[c], g = grow[c];
        const float4 m0 = hm[2 * c], m1 = hm[2 * c + 1];
        const float4 q0 = hg[2 * c], q1 = hg[2 * c + 1];
        am = fmaf(m0.x, blo(w.x), am); am = fmaf(m0.y, bhi(w.x), am);
        am = fmaf(m0.z, blo(w.y), am); am = fmaf(m0.w, bhi(w.y), am);
        am = fmaf(m1.x, blo(w.z), am); am = fmaf(m1.y, bhi(w.z), am);
        am = fmaf(m1.z, blo(w.w), am); am = fmaf(m1.w, bhi(w.w), am);
        ag = fmaf(q0.x, blo(g.x), ag); ag = fmaf(q0.y, bhi(g.x), ag);
        ag = fmaf(q0.z, blo(g.y), ag); ag = fmaf(q0.w, bhi(g.y), ag);
        ag = fmaf(q1.x, blo(g.z), ag); ag = fmaf(q1.y, bhi(g.z), ag);
        ag = fmaf(q1.z, blo(g.w), ag); ag = fmaf(q1.w, bhi(g.w), ag);
      }
      h2m[wv][lane] = fsilu(am);
      h2g[wv][lane] = fsilu(ag);
    }
    WSYNC();

    // ---- layer 3: cols j0, j0+1 ----
    {
      float am0 = b3s[j0], am1 = b3s[j0 + 1];
      float ag0 = g3s[j0], ag1 = g3s[j0 + 1];
      const uint4* wr0 = (const uint4*)&W3T[j0][0];
      const uint4* wr1 = (const uint4*)&W3T[j0 + 1][0];
      const uint4* gr0 = (const uint4*)&G3T[j0][0];
      const uint4* gr1 = (const uint4*)&G3T[j0 + 1][0];
      const float4* hm = (const float4*)&h2m[wv][0];
      const float4* hg = (const float4*)&h2g[wv][0];
#pragma unroll
      for (int c = 0; c < 8; ++c) {
        const uint4 wa = wr0[c], wb = wr1[c];
        const uint4 qa = gr0[c], qb = gr1[c];
        const float4 m0 = hm[2 * c], m1 = hm[2 * c + 1];
        const float4 q0 = hg[2 * c], q1 = hg[2 * c + 1];
        am0 = fmaf(m0.x, blo(wa.x), am0); am0 = fmaf(m0.y, bhi(wa.x), am0);
        am0 = fmaf(m0.z, blo(wa.y), am0); am0 = fmaf(m0.w, bhi(wa.y), am0);
        am0 = fmaf(m1.x, blo(wa.z), am0); am0 = fmaf(m1.y, bhi(wa.z), am0);
        am0 = fmaf(m1.z, blo(wa.w), am0); am0 = fmaf(m1.w, bhi(wa.w), am0);
        am1 = fmaf(m0.x, blo(wb.x), am1); am1 = fmaf(m0.y, bhi(wb.x), am1);
        am1 = fmaf(m0.z, blo(wb.y), am1); am1 = fmaf(m0.w, bhi(wb.y), am1);
        am1 = fmaf(m1.x, blo(wb.z), am1); am1 = fmaf(m1.y, bhi(wb.z), am1);
        am1 = fmaf(m1.z, blo(wb.w), am1); am1 = fmaf(m1.w, bhi(wb.w), am1);
        ag0 = fmaf(q0.x, blo(qa.x), ag0); ag0 = fmaf(q0.y, bhi(qa.x), ag0);
        ag0 = fmaf(q0.z, blo(qa.y), ag0); ag0 = fmaf(q0.w, bhi(qa.y), ag0);
        ag0 = fmaf(q1.x, blo(qa.z), ag0); ag0 = fmaf(q1.y, bhi(qa.z), ag0);
        ag0 = fmaf(q1.z, blo(qa.w), ag0); ag0 = fmaf(q1.w, bhi(qa.w), ag0);
        ag1 = fmaf(q0.x, blo(qb.x), ag1); ag1 = fmaf(q0.y, bhi(qb.x), ag1);
        ag1 = fmaf(q0.z, blo(qb.y), ag1); ag1 = fmaf(q0.w, bhi(qb.y), ag1);
        ag1 = fmaf(q1.x, blo(qb.z), ag1); ag1 = fmaf(q1.y, bhi(qb.z), ag1);
        ag1 = fmaf(q1.z, blo(qb.w), ag1); ag1 = fmaf(q1.w, bhi(qb.w), ag1);
      }
      accA.x = fmaf(fsilu(am0) * fsig(ag0), sc, accA.x);
      accA.y = fmaf(fsilu(am1) * fsig(ag1), sc, accA.y);
    }
    WSYNC();  // h2 reads complete before next iter's h1/h2 writes
  }
  *(float2*)(out + (size_t)a * D + j0) = accA;
}

// ---------------------------------------------------------------------------
extern "C" void kernel_launch(void* const* d_in, const int* in_sizes, int n_in,
                              void* d_out, int out_size, void* d_ws, size_t ws_size,
                              hipStream_t stream) {
  const float* atom = (const float*)d_in[0];
  const float* ea   = (const float*)d_in[1];
  const float* eap  = (const float*)d_in[2];
  const int*   ei   = (const int*)d_in[3];
  const float* W1 = (const float*)d_in[5];
  const float* b1 = (const float*)d_in[6];
  const float* W2 = (const float*)d_in[7];
  const float* b2 = (const float*)d_in[8];
  const float* W3 = (const float*)d_in[9];
  const float* b3 = (const float*)d_in[10];
  const float* G1 = (const float*)d_in[11];
  const float* g1 = (const float*)d_in[12];
  const float* G2 = (const float*)d_in[13];
  const float* g2 = (const float*)d_in[14];
  const float* G3 = (const float*)d_in[15];
  const float* g3 = (const float*)d_in[16];
  const float* We = (const float*)d_in[17];
  const float* be = (const float*)d_in[18];
  float* out = (float*)d_out;

  // ws layout: 4 bf16 tables (102.4MB) + counts + roff + cursor + perm (~7.2MB)
  char* w = (char*)d_ws;
  bf16* PA  = (bf16*)w;                     w += (size_t)N_ATOMS * D * 2;
  bf16* PB  = (bf16*)w;                     w += (size_t)N_ATOMS * D * 2;
  bf16* PGA = (bf16*)w;                     w += (size_t)N_ATOMS * D * 2;
  bf16* PGB = (bf16*)w;                     w += (size_t)N_ATOMS * D * 2;
  int* counts = (int*)w;                    w += (size_t)N_ATOMS * 4;
  int* roff   = (int*)w;                    w += (size_t)(N_ATOMS + 4) * 4;
  int* cursor = (int*)w;                    w += (size_t)N_ATOMS * 4;
  int* perm   = (int*)w;                    w += (size_t)N_EDGES * 4;

  hipMemsetAsync(counts, 0, (size_t)N_ATOMS * 4, stream);
  hipMemsetAsync(cursor, 0, (size_t)N_ATOMS * 4, stream);

  hipLaunchKernelGGL(k_tables, dim3(N_ATOMS / 32), dim3(256), 0, stream,
                     atom, W1, G1, PA, PB, PGA, PGB);
  hipLaunchKernelGGL(k_hist, dim3((N_EDGES + 255) / 256), dim3(256), 0, stream, ei, counts);
  hipLaunchKernelGGL(k_scan, dim3(1), dim3(1024), 0, stream, counts, roff);
  hipLaunchKernelGGL(k_scatter, dim3((N_EDGES + 255) / 256), dim3(256), 0, stream,
                     ei, roff, cursor, perm);
  hipLaunchKernelGGL(k_atoms, dim3((N_ATOMS + WPB - 1) / WPB), dim3(1024), 0, stream,
                     atom, ea, eap, ei, roff, perm, PA, PB, PGA, PGB,
                     W1, G1, b1, g1, W2, b2, W3, b3, G2, g2, G3, g3, We, be, out);
}

// Round 4
// 2019.554 us; speedup vs baseline: 18.4851x; 2.8457x over previous
//
#include <hip/hip_runtime.h>
#include <hip/hip_bf16.h>

#define N_ATOMS 100000
#define N_EDGES 1600000
#define D       128
#define DE      100
#define DSPH    9

typedef __hip_bfloat16 bf16;
typedef unsigned short ushort_t;
typedef short s16x8 __attribute__((ext_vector_type(8)));   // 8 bf16 (4 VGPR)
typedef float f32x4 __attribute__((ext_vector_type(4)));   // MFMA acc

#define MFMA16(a, b, c) __builtin_amdgcn_mfma_f32_16x16x32_bf16(a, b, c, 0, 0, 0)

__device__ __forceinline__ float blo(unsigned int u) {
  union { unsigned int i; float f; } v; v.i = u << 16; return v.f;
}
__device__ __forceinline__ float bhi(unsigned int u) {
  union { unsigned int i; float f; } v; v.i = u & 0xffff0000u; return v.f;
}
__device__ __forceinline__ unsigned short f2b(float x) {
  bf16 h = __float2bfloat16(x);
  return *(unsigned short*)&h;
}
__device__ __forceinline__ float fsig(float x) {
  return __builtin_amdgcn_rcpf(1.0f + __expf(-x));
}
__device__ __forceinline__ float fsilu(float x) { return x * fsig(x); }

// ---------------------------------------------------------------------------
// Kernel 1: per-atom partial layer-1 products (bf16 tables).
// ---------------------------------------------------------------------------
__global__ __launch_bounds__(256) void k_tables(
    const float* __restrict__ atom, const float* __restrict__ W1,
    const float* __restrict__ G1,
    bf16* __restrict__ PA, bf16* __restrict__ PB,
    bf16* __restrict__ PGA, bf16* __restrict__ PGB)
{
  __shared__ __align__(16) float at[32][132];
  const int tid = threadIdx.x;
  const size_t abase = (size_t)blockIdx.x * 32;

  for (int i = tid; i < 1024; i += 256) {
    int a = i >> 5, c = i & 31;
    *(float4*)&at[a][c * 4] = ((const float4*)(atom + (abase + a) * D))[c];
  }
  __syncthreads();

  const int tj = tid & 15;
  const int ta = tid >> 4;

  for (int t = 0; t < 4; ++t) {
    const float* W = ((t < 2) ? W1 : G1) + (t & 1) * (D * D);
    bf16* P = (t == 0) ? PA : (t == 1) ? PB : (t == 2) ? PGA : PGB;
    float acc0[8], acc1[8];
#pragma unroll
    for (int c = 0; c < 8; ++c) { acc0[c] = 0.f; acc1[c] = 0.f; }
#pragma unroll 4
    for (int k = 0; k < D; ++k) {
      const float a0 = at[ta * 2][k];
      const float a1 = at[ta * 2 + 1][k];
      const float4 w0 = *(const float4*)&W[k * D + tj * 8];
      const float4 w1 = *(const float4*)&W[k * D + tj * 8 + 4];
      acc0[0] = fmaf(a0, w0.x, acc0[0]); acc1[0] = fmaf(a1, w0.x, acc1[0]);
      acc0[1] = fmaf(a0, w0.y, acc0[1]); acc1[1] = fmaf(a1, w0.y, acc1[1]);
      acc0[2] = fmaf(a0, w0.z, acc0[2]); acc1[2] = fmaf(a1, w0.z, acc1[2]);
      acc0[3] = fmaf(a0, w0.w, acc0[3]); acc1[3] = fmaf(a1, w0.w, acc1[3]);
      acc0[4] = fmaf(a0, w1.x, acc0[4]); acc1[4] = fmaf(a1, w1.x, acc1[4]);
      acc0[5] = fmaf(a0, w1.y, acc0[5]); acc1[5] = fmaf(a1, w1.y, acc1[5]);
      acc0[6] = fmaf(a0, w1.z, acc0[6]); acc1[6] = fmaf(a1, w1.z, acc1[6]);
      acc0[7] = fmaf(a0, w1.w, acc0[7]); acc1[7] = fmaf(a1, w1.w, acc1[7]);
    }
    bf16* p0 = P + (abase + ta * 2) * D + tj * 8;
    bf16* p1 = p0 + D;
#pragma unroll
    for (int c = 0; c < 8; ++c) {
      p0[c] = __float2bfloat16(acc0[c]);
      p1[c] = __float2bfloat16(acc1[c]);
    }
  }
}

// ---------------------------------------------------------------------------
// CSR build: histogram -> scan -> scatter (dst-sorted edge permutation)
// ---------------------------------------------------------------------------
__global__ __launch_bounds__(256) void k_hist(const int* __restrict__ ei,
                                              int* __restrict__ counts) {
  int e = blockIdx.x * 256 + threadIdx.x;
  if (e < N_EDGES) atomicAdd(&counts[ei[N_EDGES + e]], 1);
}

__global__ __launch_bounds__(1024) void k_scan(const int* __restrict__ counts,
                                               int* __restrict__ roff) {
  __shared__ int ssum[1024];
  const int tid = threadIdx.x;
  const int CH = (N_ATOMS + 1023) / 1024;
  const int base = tid * CH;
  int s = 0;
  for (int k = 0; k < CH; ++k) {
    int idx = base + k;
    if (idx < N_ATOMS) s += counts[idx];
  }
  ssum[tid] = s;
  __syncthreads();
  for (int off = 1; off < 1024; off <<= 1) {
    int v = 0;
    if (tid >= off) v = ssum[tid - off];
    __syncthreads();
    if (tid >= off) ssum[tid] += v;
    __syncthreads();
  }
  s = (tid == 0) ? 0 : ssum[tid - 1];
  for (int k = 0; k < CH; ++k) {
    int idx = base + k;
    if (idx < N_ATOMS) { roff[idx] = s; s += counts[idx]; }
  }
  if (tid == 1023) roff[N_ATOMS] = s;
}

__global__ __launch_bounds__(256) void k_scatter(const int* __restrict__ ei,
                                                 const int* __restrict__ roff,
                                                 int* __restrict__ cursor,
                                                 int* __restrict__ perm) {
  int e = blockIdx.x * 256 + threadIdx.x;
  if (e < N_EDGES) {
    int d = ei[N_EDGES + e];
    int p = atomicAdd(&cursor[d], 1);
    perm[roff[d] + p] = e;
  }
}

// ---------------------------------------------------------------------------
// out = atom_attr (residual base; tile kernel atomically adds on top)
// ---------------------------------------------------------------------------
__global__ void k_init(const float4* __restrict__ a, float4* __restrict__ o, int n4) {
  int i = blockIdx.x * blockDim.x + threadIdx.x;
  const int st = gridDim.x * blockDim.x;
  for (; i < n4; i += st) o[i] = a[i];
}

// ---------------------------------------------------------------------------
// k_wprep: materialize per-(tid,frag) bf16 B-operand fragments once.
// Layout: WF[frag][tid] -> s16x8. frag order:
//   0,1: B1m[q]   2,3: B1g[q]
//   4..7: B2m[ks] 8..11: B2g[ks]
//   12..15: B3m[q][ks] (2q+ks)   16..19: B3g[q][ks]
// ---------------------------------------------------------------------------
__global__ __launch_bounds__(256) void k_wprep(
    const float* __restrict__ W1, const float* __restrict__ b1,
    const float* __restrict__ W2, const float* __restrict__ W3,
    const float* __restrict__ G1, const float* __restrict__ g1v,
    const float* __restrict__ G2, const float* __restrict__ G3,
    ushort_t* __restrict__ WF)
{
  const int tid = threadIdx.x;
  const int lane = tid & 63, w = tid >> 6, fr = lane & 15, fg = lane >> 4;
  s16x8 fb[20];
#pragma unroll
  for (int q = 0; q < 2; ++q) {
    const int j = 16 * (2 * w + q) + fr;
    s16x8 bm, bg;
#pragma unroll
    for (int kk = 0; kk < 8; ++kk) {
      const int k = 8 * fg + kk;
      short vm = 0, vg = 0;
      if (k < 9)        { vm = (short)f2b(W1[(256 + k) * 128 + j]); vg = (short)f2b(G1[(256 + k) * 128 + j]); }
      else if (k == 31) { vm = (short)f2b(b1[j]);                    vg = (short)f2b(g1v[j]); }
      bm[kk] = vm; bg[kk] = vg;
    }
    fb[0 + q] = bm; fb[2 + q] = bg;
  }
  {
    const int j = 16 * w + fr;
#pragma unroll
    for (int ks = 0; ks < 4; ++ks) {
      s16x8 bm, bg;
#pragma unroll
      for (int kk = 0; kk < 8; ++kk) {
        const int k = 32 * ks + 8 * fg + kk;
        bm[kk] = (short)f2b(W2[k * 64 + j]);
        bg[kk] = (short)f2b(G2[k * 64 + j]);
      }
      fb[4 + ks] = bm; fb[8 + ks] = bg;
    }
  }
#pragma unroll
  for (int q = 0; q < 2; ++q) {
    const int j = 16 * (2 * w + q) + fr;
#pragma unroll
    for (int ks = 0; ks < 2; ++ks) {
      s16x8 bm, bg;
#pragma unroll
      for (int kk = 0; kk < 8; ++kk) {
        const int k = 32 * ks + 8 * fg + kk;
        bm[kk] = (short)f2b(W3[k * 128 + j]);
        bg[kk] = (short)f2b(G3[k * 128 + j]);
      }
      fb[12 + 2 * q + ks] = bm; fb[16 + 2 * q + ks] = bg;
    }
  }
#pragma unroll
  for (int f = 0; f < 20; ++f)
    ((s16x8*)WF)[f * 256 + tid] = fb[f];
}

// ---------------------------------------------------------------------------
// k_tile: 64 dst-sorted edges per block, 256 thr (4 waves).
// MFMA gated MLP; B-operands in registers; in-LDS segmented reduce + atomics.
// ---------------------------------------------------------------------------
#define OFF_SAB 0
#define OFF_H2M 0
#define OFF_H2G 8192
#define OFF_SPH 32768
#define OFF_H1M 36864
#define OFF_H1G 53248
#define OFF_MSG 36864
#define OFF_DST 69632
#define OFF_SC  69888
#define OFF_SRC 70144
#define OFF_E   70400

__global__ __launch_bounds__(256, 2) void k_tile(
    const float* __restrict__ ea, const float* __restrict__ eap,
    const int*  __restrict__ ei, const int* __restrict__ perm,
    const ushort_t* __restrict__ PA, const ushort_t* __restrict__ PB,
    const ushort_t* __restrict__ PGA, const ushort_t* __restrict__ PGB,
    const ushort_t* __restrict__ WF,
    const float* __restrict__ b2v, const float* __restrict__ g2v,
    const float* __restrict__ b3v, const float* __restrict__ g3v,
    const float* __restrict__ We, const float* __restrict__ be,
    float* __restrict__ out)
{
  __shared__ __align__(16) char BUF[70656];
  const int tid  = threadIdx.x;
  const int lane = tid & 63;
  const int w    = tid >> 6;        // wave 0..3
  const int fr   = lane & 15;       // frag row
  const int fg   = lane >> 4;       // frag k-group / C row-group
  const long E0  = (long)blockIdx.x * 64;

  int*   e_s   = (int*)(BUF + OFF_E);
  int*   src_s = (int*)(BUF + OFF_SRC);
  int*   dst_s = (int*)(BUF + OFF_DST);
  float* sc_s  = (float*)(BUF + OFF_SC);

  // ---- phase 1: edge indices + sph pad-fill (k=10..31; k31 slot = 1.0) ----
  if (tid < 64) {
    const int e = perm[E0 + tid];
    e_s[tid]   = e;
    src_s[tid] = ei[e];
    dst_s[tid] = ei[N_EDGES + e];
  }
  for (int idx = tid; idx < 64 * 11; idx += 256) {
    const int i = idx / 11, ww = 5 + idx % 11;
    ((unsigned int*)(BUF + OFF_SPH))[i * 16 + ww] = (ww == 15) ? 0x3F800000u : 0u;
  }

  // ---- prologue: weight fragments (precomputed, coalesced dwordx4) ----
  const s16x8* WFv = (const s16x8*)WF;
  s16x8 B1m[2], B1g[2], B2m[4], B2g[4], B3m[2][2], B3g[2][2];
#pragma unroll
  for (int q = 0; q < 2; ++q) { B1m[q] = WFv[(0 + q) * 256 + tid]; B1g[q] = WFv[(2 + q) * 256 + tid]; }
#pragma unroll
  for (int ks = 0; ks < 4; ++ks) { B2m[ks] = WFv[(4 + ks) * 256 + tid]; B2g[ks] = WFv[(8 + ks) * 256 + tid]; }
#pragma unroll
  for (int q = 0; q < 2; ++q)
#pragma unroll
    for (int ks = 0; ks < 2; ++ks) {
      B3m[q][ks] = WFv[(12 + 2 * q + ks) * 256 + tid];
      B3g[q][ks] = WFv[(16 + 2 * q + ks) * 256 + tid];
    }
  const float b2j = b2v[16 * w + fr], g2j = g2v[16 * w + fr];
  const float b3j0 = b3v[16 * 2 * w + fr],       g3j0 = g3v[16 * 2 * w + fr];
  const float b3j1 = b3v[16 * (2 * w + 1) + fr], g3j1 = g3v[16 * (2 * w + 1) + fr];
  const float beV = be[0];
  const float wlo = We[lane];
  const float whi = (lane < 36) ? We[64 + lane] : 0.f;
  __syncthreads();   // bar A: e_s/src/dst + sph pad visible

  // ---- phase 2: sph fill (k<10), SAB pair-sums, per-edge scalars ----
  for (int idx = tid; idx < 640; idx += 256) {
    const int i = idx / 10, k = idx % 10;
    unsigned short v = 0;
    if (k < 9) v = f2b(eap[(size_t)e_s[i] * DSPH + k]);
    *(unsigned short*)(BUF + OFF_SPH + i * 64 + k * 2) = v;
  }
  for (int idx = tid; idx < 1024; idx += 256) {
    const int i = idx >> 4, cc = (idx & 15) * 8;
    const uint4 pa  = *(const uint4*)(PA  + (size_t)src_s[i] * 128 + cc);
    const uint4 pb  = *(const uint4*)(PB  + (size_t)dst_s[i] * 128 + cc);
    const uint4 pga = *(const uint4*)(PGA + (size_t)src_s[i] * 128 + cc);
    const uint4 pgb = *(const uint4*)(PGB + (size_t)dst_s[i] * 128 + cc);
    uint4 o0, o1;
    o0.x = (unsigned)f2b(blo(pa.x) + blo(pb.x)) | ((unsigned)f2b(blo(pga.x) + blo(pgb.x)) << 16);
    o0.y = (unsigned)f2b(bhi(pa.x) + bhi(pb.x)) | ((unsigned)f2b(bhi(pga.x) + bhi(pgb.x)) << 16);
    o0.z = (unsigned)f2b(blo(pa.y) + blo(pb.y)) | ((unsigned)f2b(blo(pga.y) + blo(pgb.y)) << 16);
    o0.w = (unsigned)f2b(bhi(pa.y) + bhi(pb.y)) | ((unsigned)f2b(bhi(pga.y) + bhi(pgb.y)) << 16);
    o1.x = (unsigned)f2b(blo(pa.z) + blo(pb.z)) | ((unsigned)f2b(blo(pga.z) + blo(pgb.z)) << 16);
    o1.y = (unsigned)f2b(bhi(pa.z) + bhi(pb.z)) | ((unsigned)f2b(bhi(pga.z) + bhi(pgb.z)) << 16);
    o1.z = (unsigned)f2b(blo(pa.w) + blo(pb.w)) | ((unsigned)f2b(blo(pga.w) + blo(pgb.w)) << 16);
    o1.w = (unsigned)f2b(bhi(pa.w) + bhi(pb.w)) | ((unsigned)f2b(bhi(pga.w) + bhi(pgb.w)) << 16);
    uint4* dst4 = (uint4*)(BUF + OFF_SAB + i * 512 + cc * 4);
    dst4[0] = o0; dst4[1] = o1;
  }
  for (int ii = 0; ii < 16; ++ii) {       // per-edge scalar, wave-per-16-edges
    const int i = 16 * w + ii;
    const size_t eb = (size_t)e_s[i] * DE;
    float s = ea[eb + lane] * wlo + ((lane < 36) ? ea[eb + 64 + lane] * whi : 0.f);
#pragma unroll
    for (int o = 32; o; o >>= 1) s += __shfl_xor(s, o);
    if (lane == 0) sc_s[i] = s + beV;
  }
  __syncthreads();   // bar B: sph/SAB/sc visible

  // ---- L1: Z1 = sph @ W1cT(+bias) ; epilogue adds SAB, silu -> H1 ----
  f32x4 a1m[4][2], a1g[4][2];
#pragma unroll
  for (int me = 0; me < 4; ++me)
#pragma unroll
    for (int q = 0; q < 2; ++q) { a1m[me][q] = (f32x4){0.f,0.f,0.f,0.f}; a1g[me][q] = (f32x4){0.f,0.f,0.f,0.f}; }
#pragma unroll
  for (int me = 0; me < 4; ++me) {
    const s16x8 a = *(const s16x8*)(BUF + OFF_SPH + (16 * me + fr) * 64 + fg * 16);
#pragma unroll
    for (int q = 0; q < 2; ++q) {
      a1m[me][q] = MFMA16(a, B1m[q], a1m[me][q]);
      a1g[me][q] = MFMA16(a, B1g[q], a1g[me][q]);
    }
  }
#pragma unroll
  for (int me = 0; me < 4; ++me)
#pragma unroll
    for (int q = 0; q < 2; ++q) {
      const int col = 16 * (2 * w + q) + fr;
#pragma unroll
      for (int r = 0; r < 4; ++r) {
        const int e = 16 * me + 4 * fg + r;
        const unsigned v = *(const unsigned*)(BUF + OFF_SAB + e * 512 + col * 4);
        const unsigned short hm = f2b(fsilu(a1m[me][q][r] + blo(v)));
        const unsigned short hg = f2b(fsilu(a1g[me][q][r] + bhi(v)));
        const int cb = (col * 2) ^ ((e & 15) << 4);
        *(unsigned short*)(BUF + OFF_H1M + e * 256 + cb) = hm;
        *(unsigned short*)(BUF + OFF_H1G + e * 256 + cb) = hg;
      }
    }
  __syncthreads();   // bar C

  // ---- L2: Z2 = H1 @ W2 (+b2) ; silu -> H2 (overlays SAB region) ----
  f32x4 a2m[4], a2g[4];
#pragma unroll
  for (int me = 0; me < 4; ++me) { a2m[me] = (f32x4){b2j,b2j,b2j,b2j}; a2g[me] = (f32x4){g2j,g2j,g2j,g2j}; }
#pragma unroll
  for (int me = 0; me < 4; ++me) {
    const int row = 16 * me + fr;
#pragma unroll
    for (int ks = 0; ks < 4; ++ks) {
      const int cb = (64 * ks + 16 * fg) ^ ((row & 15) << 4);
      const s16x8 am = *(const s16x8*)(BUF + OFF_H1M + row * 256 + cb);
      const s16x8 ag = *(const s16x8*)(BUF + OFF_H1G + row * 256 + cb);
      a2m[me] = MFMA16(am, B2m[ks], a2m[me]);
      a2g[me] = MFMA16(ag, B2g[ks], a2g[me]);
    }
  }
  {
    const int j2 = 16 * w + fr;
#pragma unroll
    for (int me = 0; me < 4; ++me)
#pragma unroll
      for (int r = 0; r < 4; ++r) {
        const int e = 16 * me + 4 * fg + r;
        const int cb = (j2 * 2) ^ ((e & 7) << 4);
        *(unsigned short*)(BUF + OFF_H2M + e * 128 + cb) = f2b(fsilu(a2m[me][r]));
        *(unsigned short*)(BUF + OFF_H2G + e * 128 + cb) = f2b(fsilu(a2g[me][r]));
      }
  }
  __syncthreads();   // bar D

  // ---- L3: Z3 = H2 @ W3 (+b3) ; msg = silu*sig*sc -> MSG (overlays H1) ----
  f32x4 a3m[4][2], a3g[4][2];
#pragma unroll
  for (int me = 0; me < 4; ++me) {
    a3m[me][0] = (f32x4){b3j0,b3j0,b3j0,b3j0}; a3g[me][0] = (f32x4){g3j0,g3j0,g3j0,g3j0};
    a3m[me][1] = (f32x4){b3j1,b3j1,b3j1,b3j1}; a3g[me][1] = (f32x4){g3j1,g3j1,g3j1,g3j1};
  }
#pragma unroll
  for (int me = 0; me < 4; ++me) {
    const int row = 16 * me + fr;
#pragma unroll
    for (int ks = 0; ks < 2; ++ks) {
      // k = 32*ks + 8*fg + kk  ->  byte = 64*ks + 16*fg + 2*kk   (R3 bug: had 32*ks)
      const int cb = (64 * ks + 16 * fg) ^ ((row & 7) << 4);
      const s16x8 am = *(const s16x8*)(BUF + OFF_H2M + row * 128 + cb);
      const s16x8 ag = *(const s16x8*)(BUF + OFF_H2G + row * 128 + cb);
#pragma unroll
      for (int q = 0; q < 2; ++q) {
        a3m[me][q] = MFMA16(am, B3m[q][ks], a3m[me][q]);
        a3g[me][q] = MFMA16(ag, B3g[q][ks], a3g[me][q]);
      }
    }
  }
#pragma unroll
  for (int me = 0; me < 4; ++me)
#pragma unroll
    for (int q = 0; q < 2; ++q) {
      const int col = 16 * (2 * w + q) + fr;
#pragma unroll
      for (int r = 0; r < 4; ++r) {
        const int e = 16 * me + 4 * fg + r;
        const float msg = fsilu(a3m[me][q][r]) * fsig(a3g[me][q][r]) * sc_s[e];
        *(float*)(BUF + OFF_MSG + (e * 128 + col) * 4) = msg;
      }
    }
  __syncthreads();   // bar E

  // ---- segmented reduce over sorted dst runs; one atomic row per run ----
  {
    const int col = tid & 127, h = tid >> 7;
    const float* M = (const float*)(BUF + OFF_MSG);
    const int base = 32 * h;
    int cur = dst_s[base];
    float acc = M[base * 128 + col];
    for (int e2 = 1; e2 < 32; ++e2) {
      const int d = dst_s[base + e2];          // wave-uniform -> no divergence
      const float v = M[(base + e2) * 128 + col];
      if (d != cur) {
        atomicAdd(out + (size_t)cur * D + col, acc);
        cur = d; acc = v;
      } else acc += v;
    }
    atomicAdd(out + (size_t)cur * D + col, acc);
  }
}

// ---------------------------------------------------------------------------
extern "C" void kernel_launch(void* const* d_in, const int* in_sizes, int n_in,
                              void* d_out, int out_size, void* d_ws, size_t ws_size,
                              hipStream_t stream) {
  const float* atom = (const float*)d_in[0];
  const float* ea   = (const float*)d_in[1];
  const float* eap  = (const float*)d_in[2];
  const int*   ei   = (const int*)d_in[3];
  const float* W1 = (const float*)d_in[5];
  const float* b1 = (const float*)d_in[6];
  const float* W2 = (const float*)d_in[7];
  const float* b2 = (const float*)d_in[8];
  const float* W3 = (const float*)d_in[9];
  const float* b3 = (const float*)d_in[10];
  const float* G1 = (const float*)d_in[11];
  const float* g1 = (const float*)d_in[12];
  const float* G2 = (const float*)d_in[13];
  const float* g2 = (const float*)d_in[14];
  const float* G3 = (const float*)d_in[15];
  const float* g3 = (const float*)d_in[16];
  const float* We = (const float*)d_in[17];
  const float* be = (const float*)d_in[18];
  float* out = (float*)d_out;

  char* wp = (char*)d_ws;
  bf16* PA  = (bf16*)wp;                    wp += (size_t)N_ATOMS * D * 2;
  bf16* PB  = (bf16*)wp;                    wp += (size_t)N_ATOMS * D * 2;
  bf16* PGA = (bf16*)wp;                    wp += (size_t)N_ATOMS * D * 2;
  bf16* PGB = (bf16*)wp;                    wp += (size_t)N_ATOMS * D * 2;
  int* counts = (int*)wp;                   wp += (size_t)N_ATOMS * 4;
  int* roff   = (int*)wp;                   wp += (size_t)(N_ATOMS + 4) * 4;
  int* cursor = (int*)wp;                   wp += (size_t)N_ATOMS * 4;
  int* perm   = (int*)wp;                   wp += (size_t)N_EDGES * 4;
  ushort_t* WF = (ushort_t*)wp;             wp += (size_t)20 * 256 * 8 * 2;

  hipMemsetAsync(counts, 0, (size_t)N_ATOMS * 4, stream);
  hipMemsetAsync(cursor, 0, (size_t)N_ATOMS * 4, stream);

  hipLaunchKernelGGL(k_tables, dim3(N_ATOMS / 32), dim3(256), 0, stream,
                     atom, W1, G1, PA, PB, PGA, PGB);
  hipLaunchKernelGGL(k_wprep, dim3(1), dim3(256), 0, stream,
                     W1, b1, W2, W3, G1, g1, G2, G3, WF);
  hipLaunchKernelGGL(k_hist, dim3((N_EDGES + 255) / 256), dim3(256), 0, stream, ei, counts);
  hipLaunchKernelGGL(k_scan, dim3(1), dim3(1024), 0, stream, counts, roff);
  hipLaunchKernelGGL(k_scatter, dim3((N_EDGES + 255) / 256), dim3(256), 0, stream,
                     ei, roff, cursor, perm);
  hipLaunchKernelGGL(k_init, dim3(2048), dim3(256), 0, stream,
                     (const float4*)atom, (float4*)out, N_ATOMS * D / 4);
  hipLaunchKernelGGL(k_tile, dim3(N_EDGES / 64), dim3(256), 0, stream,
                     ea, eap, ei, perm,
                     (const ushort_t*)PA, (const ushort_t*)PB,
                     (const ushort_t*)PGA, (const ushort_t*)PGB,
                     (const ushort_t*)WF, b2, g2, b3, g3, We, be, out);
}

// Round 5
// 1711.342 us; speedup vs baseline: 21.8142x; 1.1801x over previous
//
#include <hip/hip_runtime.h>
#include <hip/hip_bf16.h>

#define N_ATOMS 100000
#define N_EDGES 1600000
#define D       128
#define DE      100
#define DSPH    9

typedef __hip_bfloat16 bf16;
typedef unsigned short ushort_t;
typedef short s16x8 __attribute__((ext_vector_type(8)));   // 8 bf16 (4 VGPR)
typedef float f32x4 __attribute__((ext_vector_type(4)));   // MFMA acc

#define MFMA16(a, b, c) __builtin_amdgcn_mfma_f32_16x16x32_bf16(a, b, c, 0, 0, 0)

__device__ __forceinline__ float blo(unsigned int u) {
  union { unsigned int i; float f; } v; v.i = u << 16; return v.f;
}
__device__ __forceinline__ float bhi(unsigned int u) {
  union { unsigned int i; float f; } v; v.i = u & 0xffff0000u; return v.f;
}
__device__ __forceinline__ unsigned short f2b(float x) {
  bf16 h = __float2bfloat16(x);
  return *(unsigned short*)&h;
}
__device__ __forceinline__ float fsig(float x) {
  return __builtin_amdgcn_rcpf(1.0f + __expf(-x));
}
__device__ __forceinline__ float fsilu(float x) { return x * fsig(x); }

// ---------------------------------------------------------------------------
// Kernel 1: per-atom partial layer-1 products (bf16 tables).
// All 4 tables fused in one k-loop: 4x fewer LDS broadcast reads, 64 FMA per
// ~10 overhead ops.
// ---------------------------------------------------------------------------
__global__ __launch_bounds__(256) void k_tables(
    const float* __restrict__ atom, const float* __restrict__ W1,
    const float* __restrict__ G1,
    bf16* __restrict__ PA, bf16* __restrict__ PB,
    bf16* __restrict__ PGA, bf16* __restrict__ PGB)
{
  __shared__ __align__(16) float at[32][132];
  const int tid = threadIdx.x;
  const size_t abase = (size_t)blockIdx.x * 32;

  for (int i = tid; i < 1024; i += 256) {
    int a = i >> 5, c = i & 31;
    *(float4*)&at[a][c * 4] = ((const float4*)(atom + (abase + a) * D))[c];
  }
  __syncthreads();

  const int tj = tid & 15;
  const int ta = tid >> 4;
  const float* Wt[4] = {W1, W1 + D * D, G1, G1 + D * D};

  float acc[8][8];   // [2*t+atom][col]
#pragma unroll
  for (int u = 0; u < 8; ++u)
#pragma unroll
    for (int c = 0; c < 8; ++c) acc[u][c] = 0.f;

  for (int k = 0; k < D; ++k) {
    const float a0 = at[ta * 2][k];
    const float a1 = at[ta * 2 + 1][k];
#pragma unroll
    for (int t = 0; t < 4; ++t) {
      const float4 w0 = *(const float4*)&Wt[t][k * D + tj * 8];
      const float4 w1 = *(const float4*)&Wt[t][k * D + tj * 8 + 4];
      const float wc[8] = {w0.x, w0.y, w0.z, w0.w, w1.x, w1.y, w1.z, w1.w};
#pragma unroll
      for (int c = 0; c < 8; ++c) {
        acc[2 * t][c]     = fmaf(a0, wc[c], acc[2 * t][c]);
        acc[2 * t + 1][c] = fmaf(a1, wc[c], acc[2 * t + 1][c]);
      }
    }
  }
#pragma unroll
  for (int t = 0; t < 4; ++t) {
    bf16* P = (t == 0) ? PA : (t == 1) ? PB : (t == 2) ? PGA : PGB;
    bf16* p0 = P + (abase + ta * 2) * D + tj * 8;
    bf16* p1 = p0 + D;
#pragma unroll
    for (int c = 0; c < 8; ++c) {
      p0[c] = __float2bfloat16(acc[2 * t][c]);
      p1[c] = __float2bfloat16(acc[2 * t + 1][c]);
    }
  }
}

// ---------------------------------------------------------------------------
// k_sc: per-edge scalar sc[e] = ea[e,:] @ We + be.  8 lanes per edge.
// HBM-bound streaming pass (640 MB), removes ea entirely from k_tile.
// ---------------------------------------------------------------------------
__global__ __launch_bounds__(256) void k_sc(const float* __restrict__ ea,
                                            const float* __restrict__ We,
                                            const float* __restrict__ be,
                                            float* __restrict__ sc) {
  const int tid = threadIdx.x;
  const int r = tid & 7;                       // lane within 8-lane group
  const long e = (long)blockIdx.x * 32 + (tid >> 3);
  const float4* row = (const float4*)(ea + e * DE);   // rows are 400B = 16B-aligned
  const float4* Wv = (const float4*)We;
  const float4 w0 = Wv[r], w1 = Wv[r + 8], w2 = Wv[r + 16];
  const float4 d0 = row[r], d1 = row[r + 8], d2 = row[r + 16];
  float s = d0.x * w0.x;
  s = fmaf(d0.y, w0.y, s); s = fmaf(d0.z, w0.z, s); s = fmaf(d0.w, w0.w, s);
  s = fmaf(d1.x, w1.x, s); s = fmaf(d1.y, w1.y, s); s = fmaf(d1.z, w1.z, s);
  s = fmaf(d1.w, w1.w, s); s = fmaf(d2.x, w2.x, s); s = fmaf(d2.y, w2.y, s);
  s = fmaf(d2.z, w2.z, s); s = fmaf(d2.w, w2.w, s);
  if (r == 0) {
    const float4 w3 = Wv[24], d3 = row[24];
    s = fmaf(d3.x, w3.x, s); s = fmaf(d3.y, w3.y, s);
    s = fmaf(d3.z, w3.z, s); s = fmaf(d3.w, w3.w, s);
  }
  s += __shfl_xor(s, 1); s += __shfl_xor(s, 2); s += __shfl_xor(s, 4);
  if (r == 0) sc[e] = s + be[0];
}

// ---------------------------------------------------------------------------
// CSR build: histogram -> scan -> scatter (dst-sorted edge permutation)
// ---------------------------------------------------------------------------
__global__ __launch_bounds__(256) void k_hist(const int* __restrict__ ei,
                                              int* __restrict__ counts) {
  int e = blockIdx.x * 256 + threadIdx.x;
  if (e < N_EDGES) atomicAdd(&counts[ei[N_EDGES + e]], 1);
}

__global__ __launch_bounds__(1024) void k_scan(const int* __restrict__ counts,
                                               int* __restrict__ roff) {
  __shared__ int ssum[1024];
  const int tid = threadIdx.x;
  const int CH = (N_ATOMS + 1023) / 1024;
  const int base = tid * CH;
  int s = 0;
  for (int k = 0; k < CH; ++k) {
    int idx = base + k;
    if (idx < N_ATOMS) s += counts[idx];
  }
  ssum[tid] = s;
  __syncthreads();
  for (int off = 1; off < 1024; off <<= 1) {
    int v = 0;
    if (tid >= off) v = ssum[tid - off];
    __syncthreads();
    if (tid >= off) ssum[tid] += v;
    __syncthreads();
  }
  s = (tid == 0) ? 0 : ssum[tid - 1];
  for (int k = 0; k < CH; ++k) {
    int idx = base + k;
    if (idx < N_ATOMS) { roff[idx] = s; s += counts[idx]; }
  }
  if (tid == 1023) roff[N_ATOMS] = s;
}

__global__ __launch_bounds__(256) void k_scatter(const int* __restrict__ ei,
                                                 const int* __restrict__ roff,
                                                 int* __restrict__ cursor,
                                                 int* __restrict__ perm) {
  int e = blockIdx.x * 256 + threadIdx.x;
  if (e < N_EDGES) {
    int d = ei[N_EDGES + e];
    int p = atomicAdd(&cursor[d], 1);
    perm[roff[d] + p] = e;
  }
}

// ---------------------------------------------------------------------------
// out = atom_attr (residual base; tile kernel atomically adds on top)
// ---------------------------------------------------------------------------
__global__ void k_init(const float4* __restrict__ a, float4* __restrict__ o, int n4) {
  int i = blockIdx.x * blockDim.x + threadIdx.x;
  const int st = gridDim.x * blockDim.x;
  for (; i < n4; i += st) o[i] = a[i];
}

// ---------------------------------------------------------------------------
// k_wprep: materialize per-(tid,frag) bf16 B-operand fragments once.
// ---------------------------------------------------------------------------
__global__ __launch_bounds__(256) void k_wprep(
    const float* __restrict__ W1, const float* __restrict__ b1,
    const float* __restrict__ W2, const float* __restrict__ W3,
    const float* __restrict__ G1, const float* __restrict__ g1v,
    const float* __restrict__ G2, const float* __restrict__ G3,
    ushort_t* __restrict__ WF)
{
  const int tid = threadIdx.x;
  const int lane = tid & 63, w = tid >> 6, fr = lane & 15, fg = lane >> 4;
  s16x8 fb[20];
#pragma unroll
  for (int q = 0; q < 2; ++q) {
    const int j = 16 * (2 * w + q) + fr;
    s16x8 bm, bg;
#pragma unroll
    for (int kk = 0; kk < 8; ++kk) {
      const int k = 8 * fg + kk;
      short vm = 0, vg = 0;
      if (k < 9)        { vm = (short)f2b(W1[(256 + k) * 128 + j]); vg = (short)f2b(G1[(256 + k) * 128 + j]); }
      else if (k == 31) { vm = (short)f2b(b1[j]);                    vg = (short)f2b(g1v[j]); }
      bm[kk] = vm; bg[kk] = vg;
    }
    fb[0 + q] = bm; fb[2 + q] = bg;
  }
  {
    const int j = 16 * w + fr;
#pragma unroll
    for (int ks = 0; ks < 4; ++ks) {
      s16x8 bm, bg;
#pragma unroll
      for (int kk = 0; kk < 8; ++kk) {
        const int k = 32 * ks + 8 * fg + kk;
        bm[kk] = (short)f2b(W2[k * 64 + j]);
        bg[kk] = (short)f2b(G2[k * 64 + j]);
      }
      fb[4 + ks] = bm; fb[8 + ks] = bg;
    }
  }
#pragma unroll
  for (int q = 0; q < 2; ++q) {
    const int j = 16 * (2 * w + q) + fr;
#pragma unroll
    for (int ks = 0; ks < 2; ++ks) {
      s16x8 bm, bg;
#pragma unroll
      for (int kk = 0; kk < 8; ++kk) {
        const int k = 32 * ks + 8 * fg + kk;
        bm[kk] = (short)f2b(W3[k * 128 + j]);
        bg[kk] = (short)f2b(G3[k * 128 + j]);
      }
      fb[12 + 2 * q + ks] = bm; fb[16 + 2 * q + ks] = bg;
    }
  }
#pragma unroll
  for (int f = 0; f < 20; ++f)
    ((s16x8*)WF)[f * 256 + tid] = fb[f];
}

// ---------------------------------------------------------------------------
// k_tile: 64 dst-sorted edges per block, 256 thr (4 waves), 3 blocks/CU.
// LDS overlay (50176 B):
//   X [0,32K):  SAB (ph2..L1epi1) -> H1M/H1G (L1epi2..L2) -> MSG (L3epi..reduce)
//   Y [32K,48K): sph [32K,36K) (ph1..L1 main) -> H2M [32K,40K)+H2G [40K,48K)
//   tails [48K,50K): dst, sc, src, e
// ---------------------------------------------------------------------------
#define OFF_SAB 0
#define OFF_H1M 0
#define OFF_H1G 16384
#define OFF_MSG 0
#define OFF_SPH 32768
#define OFF_H2M 32768
#define OFF_H2G 40960
#define OFF_DST 49152
#define OFF_SC  49408
#define OFF_SRC 49664
#define OFF_E   49920

__global__ __launch_bounds__(256, 3) void k_tile(
    const float* __restrict__ eap,
    const int*  __restrict__ ei, const int* __restrict__ perm,
    const ushort_t* __restrict__ PA, const ushort_t* __restrict__ PB,
    const ushort_t* __restrict__ PGA, const ushort_t* __restrict__ PGB,
    const ushort_t* __restrict__ WF,
    const float* __restrict__ b2v, const float* __restrict__ g2v,
    const float* __restrict__ b3v, const float* __restrict__ g3v,
    const float* __restrict__ sc_all,
    float* __restrict__ out)
{
  __shared__ __align__(16) char BUF[50176];
  const int tid  = threadIdx.x;
  const int lane = tid & 63;
  const int w    = tid >> 6;        // wave 0..3
  const int fr   = lane & 15;       // frag row
  const int fg   = lane >> 4;       // frag k-group / C row-group
  const long E0  = (long)blockIdx.x * 64;

  int*   e_s   = (int*)(BUF + OFF_E);
  int*   src_s = (int*)(BUF + OFF_SRC);
  int*   dst_s = (int*)(BUF + OFF_DST);
  float* sc_s  = (float*)(BUF + OFF_SC);

  // ---- phase 1: edge indices + precomputed scalar + sph pad-fill ----
  if (tid < 64) {
    const int e = perm[E0 + tid];
    e_s[tid]   = e;
    src_s[tid] = ei[e];
    dst_s[tid] = ei[N_EDGES + e];
    sc_s[tid]  = sc_all[e];
  }
  for (int idx = tid; idx < 64 * 11; idx += 256) {
    const int i = idx / 11, ww = 5 + idx % 11;
    ((unsigned int*)(BUF + OFF_SPH))[i * 16 + ww] = (ww == 15) ? 0x3F800000u : 0u;
  }

  // ---- prologue: weight fragments (precomputed, coalesced dwordx4) ----
  const s16x8* WFv = (const s16x8*)WF;
  s16x8 B1m[2], B1g[2], B2m[4], B2g[4], B3m[2][2], B3g[2][2];
#pragma unroll
  for (int q = 0; q < 2; ++q) { B1m[q] = WFv[(0 + q) * 256 + tid]; B1g[q] = WFv[(2 + q) * 256 + tid]; }
#pragma unroll
  for (int ks = 0; ks < 4; ++ks) { B2m[ks] = WFv[(4 + ks) * 256 + tid]; B2g[ks] = WFv[(8 + ks) * 256 + tid]; }
#pragma unroll
  for (int q = 0; q < 2; ++q)
#pragma unroll
    for (int ks = 0; ks < 2; ++ks) {
      B3m[q][ks] = WFv[(12 + 2 * q + ks) * 256 + tid];
      B3g[q][ks] = WFv[(16 + 2 * q + ks) * 256 + tid];
    }
  const float b2j = b2v[16 * w + fr], g2j = g2v[16 * w + fr];
  const float b3j0 = b3v[16 * 2 * w + fr],       g3j0 = g3v[16 * 2 * w + fr];
  const float b3j1 = b3v[16 * (2 * w + 1) + fr], g3j1 = g3v[16 * (2 * w + 1) + fr];
  __syncthreads();   // bar A: e_s/src/dst/sc + sph pad visible

  // ---- phase 2: sph fill (k<10), SAB pair-sums ----
  for (int idx = tid; idx < 640; idx += 256) {
    const int i = idx / 10, k = idx % 10;
    unsigned short v = 0;
    if (k < 9) v = f2b(eap[(size_t)e_s[i] * DSPH + k]);
    *(unsigned short*)(BUF + OFF_SPH + i * 64 + k * 2) = v;
  }
  for (int idx = tid; idx < 1024; idx += 256) {
    const int i = idx >> 4, cc = (idx & 15) * 8;
    const uint4 pa  = *(const uint4*)(PA  + (size_t)src_s[i] * 128 + cc);
    const uint4 pb  = *(const uint4*)(PB  + (size_t)dst_s[i] * 128 + cc);
    const uint4 pga = *(const uint4*)(PGA + (size_t)src_s[i] * 128 + cc);
    const uint4 pgb = *(const uint4*)(PGB + (size_t)dst_s[i] * 128 + cc);
    uint4 o0, o1;
    o0.x = (unsigned)f2b(blo(pa.x) + blo(pb.x)) | ((unsigned)f2b(blo(pga.x) + blo(pgb.x)) << 16);
    o0.y = (unsigned)f2b(bhi(pa.x) + bhi(pb.x)) | ((unsigned)f2b(bhi(pga.x) + bhi(pgb.x)) << 16);
    o0.z = (unsigned)f2b(blo(pa.y) + blo(pb.y)) | ((unsigned)f2b(blo(pga.y) + blo(pgb.y)) << 16);
    o0.w = (unsigned)f2b(bhi(pa.y) + bhi(pb.y)) | ((unsigned)f2b(bhi(pga.y) + bhi(pgb.y)) << 16);
    o1.x = (unsigned)f2b(blo(pa.z) + blo(pb.z)) | ((unsigned)f2b(blo(pga.z) + blo(pgb.z)) << 16);
    o1.y = (unsigned)f2b(bhi(pa.z) + bhi(pb.z)) | ((unsigned)f2b(bhi(pga.z) + bhi(pgb.z)) << 16);
    o1.z = (unsigned)f2b(blo(pa.w) + blo(pb.w)) | ((unsigned)f2b(blo(pga.w) + blo(pgb.w)) << 16);
    o1.w = (unsigned)f2b(bhi(pa.w) + bhi(pb.w)) | ((unsigned)f2b(bhi(pga.w) + bhi(pgb.w)) << 16);
    uint4* dst4 = (uint4*)(BUF + OFF_SAB + i * 512 + cc * 4);
    dst4[0] = o0; dst4[1] = o1;
  }
  __syncthreads();   // bar B: sph/SAB visible

  // ---- L1: Z1 = sph @ W1cT(+bias) ----
  f32x4 a1m[4][2], a1g[4][2];
#pragma unroll
  for (int me = 0; me < 4; ++me)
#pragma unroll
    for (int q = 0; q < 2; ++q) { a1m[me][q] = (f32x4){0.f,0.f,0.f,0.f}; a1g[me][q] = (f32x4){0.f,0.f,0.f,0.f}; }
#pragma unroll
  for (int me = 0; me < 4; ++me) {
    const s16x8 a = *(const s16x8*)(BUF + OFF_SPH + (16 * me + fr) * 64 + fg * 16);
#pragma unroll
    for (int q = 0; q < 2; ++q) {
      a1m[me][q] = MFMA16(a, B1m[q], a1m[me][q]);
      a1g[me][q] = MFMA16(a, B1g[q], a1g[me][q]);
    }
  }
  // L1 epilogue pt1: read SAB, silu -> packed regs (X region still = SAB)
  unsigned hpack[4][8];
#pragma unroll
  for (int me = 0; me < 4; ++me)
#pragma unroll
    for (int q = 0; q < 2; ++q) {
      const int col = 16 * (2 * w + q) + fr;
#pragma unroll
      for (int r = 0; r < 4; ++r) {
        const int e = 16 * me + 4 * fg + r;
        const unsigned v = *(const unsigned*)(BUF + OFF_SAB + e * 512 + col * 4);
        const unsigned hm = f2b(fsilu(a1m[me][q][r] + blo(v)));
        const unsigned hg = f2b(fsilu(a1g[me][q][r] + bhi(v)));
        hpack[me][4 * q + r] = hm | (hg << 16);
      }
    }
  __syncthreads();   // bar B2: all SAB reads done; X region becomes H1

  // L1 epilogue pt2: write H1 (swz16) into X
#pragma unroll
  for (int me = 0; me < 4; ++me)
#pragma unroll
    for (int q = 0; q < 2; ++q) {
      const int col = 16 * (2 * w + q) + fr;
#pragma unroll
      for (int r = 0; r < 4; ++r) {
        const int e = 16 * me + 4 * fg + r;
        const int cb = (col * 2) ^ ((e & 15) << 4);
        const unsigned u = hpack[me][4 * q + r];
        *(unsigned short*)(BUF + OFF_H1M + e * 256 + cb) = (unsigned short)u;
        *(unsigned short*)(BUF + OFF_H1G + e * 256 + cb) = (unsigned short)(u >> 16);
      }
    }
  __syncthreads();   // bar C

  // ---- L2: Z2 = H1 @ W2 (+b2) ; silu -> H2 (Y region) ----
  f32x4 a2m[4], a2g[4];
#pragma unroll
  for (int me = 0; me < 4; ++me) { a2m[me] = (f32x4){b2j,b2j,b2j,b2j}; a2g[me] = (f32x4){g2j,g2j,g2j,g2j}; }
#pragma unroll
  for (int me = 0; me < 4; ++me) {
    const int row = 16 * me + fr;
#pragma unroll
    for (int ks = 0; ks < 4; ++ks) {
      const int cb = (64 * ks + 16 * fg) ^ ((row & 15) << 4);
      const s16x8 am = *(const s16x8*)(BUF + OFF_H1M + row * 256 + cb);
      const s16x8 ag = *(const s16x8*)(BUF + OFF_H1G + row * 256 + cb);
      a2m[me] = MFMA16(am, B2m[ks], a2m[me]);
      a2g[me] = MFMA16(ag, B2g[ks], a2g[me]);
    }
  }
  {
    const int j2 = 16 * w + fr;
#pragma unroll
    for (int me = 0; me < 4; ++me)
#pragma unroll
      for (int r = 0; r < 4; ++r) {
        const int e = 16 * me + 4 * fg + r;
        const int cb = (j2 * 2) ^ ((e & 7) << 4);
        *(unsigned short*)(BUF + OFF_H2M + e * 128 + cb) = f2b(fsilu(a2m[me][r]));
        *(unsigned short*)(BUF + OFF_H2G + e * 128 + cb) = f2b(fsilu(a2g[me][r]));
      }
  }
  __syncthreads();   // bar D

  // ---- L3: Z3 = H2 @ W3 (+b3) ; msg = silu*sig*sc -> MSG (X region) ----
  f32x4 a3m[4][2], a3g[4][2];
#pragma unroll
  for (int me = 0; me < 4; ++me) {
    a3m[me][0] = (f32x4){b3j0,b3j0,b3j0,b3j0}; a3g[me][0] = (f32x4){g3j0,g3j0,g3j0,g3j0};
    a3m[me][1] = (f32x4){b3j1,b3j1,b3j1,b3j1}; a3g[me][1] = (f32x4){g3j1,g3j1,g3j1,g3j1};
  }
#pragma unroll
  for (int me = 0; me < 4; ++me) {
    const int row = 16 * me + fr;
#pragma unroll
    for (int ks = 0; ks < 2; ++ks) {
      const int cb = (64 * ks + 16 * fg) ^ ((row & 7) << 4);
      const s16x8 am = *(const s16x8*)(BUF + OFF_H2M + row * 128 + cb);
      const s16x8 ag = *(const s16x8*)(BUF + OFF_H2G + row * 128 + cb);
#pragma unroll
      for (int q = 0; q < 2; ++q) {
        a3m[me][q] = MFMA16(am, B3m[q][ks], a3m[me][q]);
        a3g[me][q] = MFMA16(ag, B3g[q][ks], a3g[me][q]);
      }
    }
  }
#pragma unroll
  for (int me = 0; me < 4; ++me)
#pragma unroll
    for (int q = 0; q < 2; ++q) {
      const int col = 16 * (2 * w + q) + fr;
#pragma unroll
      for (int r = 0; r < 4; ++r) {
        const int e = 16 * me + 4 * fg + r;
        const float msg = fsilu(a3m[me][q][r]) * fsig(a3g[me][q][r]) * sc_s[e];
        *(float*)(BUF + OFF_MSG + (e * 128 + col) * 4) = msg;
      }
    }
  __syncthreads();   // bar E

  // ---- segmented reduce: col-pair x edge-quarter (16-long chains) ----
  {
    const int cp = tid & 63;          // cols 2cp, 2cp+1
    const int qt = tid >> 6;          // quarter 0..3 (wave-uniform)
    const int base = 16 * qt;
    int cur = dst_s[base];
    float2 acc = *(const float2*)(BUF + OFF_MSG + (base * 128 + 2 * cp) * 4);
    for (int e2 = 1; e2 < 16; ++e2) {
      const int d = dst_s[base + e2];
      const float2 v = *(const float2*)(BUF + OFF_MSG + ((base + e2) * 128 + 2 * cp) * 4);
      if (d != cur) {
        atomicAdd(out + (size_t)cur * D + 2 * cp,     acc.x);
        atomicAdd(out + (size_t)cur * D + 2 * cp + 1, acc.y);
        cur = d; acc = v;
      } else { acc.x += v.x; acc.y += v.y; }
    }
    atomicAdd(out + (size_t)cur * D + 2 * cp,     acc.x);
    atomicAdd(out + (size_t)cur * D + 2 * cp + 1, acc.y);
  }
}

// ---------------------------------------------------------------------------
extern "C" void kernel_launch(void* const* d_in, const int* in_sizes, int n_in,
                              void* d_out, int out_size, void* d_ws, size_t ws_size,
                              hipStream_t stream) {
  const float* atom = (const float*)d_in[0];
  const float* ea   = (const float*)d_in[1];
  const float* eap  = (const float*)d_in[2];
  const int*   ei   = (const int*)d_in[3];
  const float* W1 = (const float*)d_in[5];
  const float* b1 = (const float*)d_in[6];
  const float* W2 = (const float*)d_in[7];
  const float* b2 = (const float*)d_in[8];
  const float* W3 = (const float*)d_in[9];
  const float* b3 = (const float*)d_in[10];
  const float* G1 = (const float*)d_in[11];
  const float* g1 = (const float*)d_in[12];
  const float* G2 = (const float*)d_in[13];
  const float* g2 = (const float*)d_in[14];
  const float* G3 = (const float*)d_in[15];
  const float* g3 = (const float*)d_in[16];
  const float* We = (const float*)d_in[17];
  const float* be = (const float*)d_in[18];
  float* out = (float*)d_out;

  char* wp = (char*)d_ws;
  bf16* PA  = (bf16*)wp;                    wp += (size_t)N_ATOMS * D * 2;
  bf16* PB  = (bf16*)wp;                    wp += (size_t)N_ATOMS * D * 2;
  bf16* PGA = (bf16*)wp;                    wp += (size_t)N_ATOMS * D * 2;
  bf16* PGB = (bf16*)wp;                    wp += (size_t)N_ATOMS * D * 2;
  int* counts = (int*)wp;                   wp += (size_t)N_ATOMS * 4;
  int* roff   = (int*)wp;                   wp += (size_t)(N_ATOMS + 4) * 4;
  int* cursor = (int*)wp;                   wp += (size_t)N_ATOMS * 4;
  int* perm   = (int*)wp;                   wp += (size_t)N_EDGES * 4;
  ushort_t* WF = (ushort_t*)wp;             wp += (size_t)20 * 256 * 8 * 2;
  float* sc_all = (float*)wp;               wp += (size_t)N_EDGES * 4;

  hipMemsetAsync(counts, 0, (size_t)N_ATOMS * 4, stream);
  hipMemsetAsync(cursor, 0, (size_t)N_ATOMS * 4, stream);

  hipLaunchKernelGGL(k_tables, dim3(N_ATOMS / 32), dim3(256), 0, stream,
                     atom, W1, G1, PA, PB, PGA, PGB);
  hipLaunchKernelGGL(k_wprep, dim3(1), dim3(256), 0, stream,
                     W1, b1, W2, W3, G1, g1, G2, G3, WF);
  hipLaunchKernelGGL(k_sc, dim3(N_EDGES / 32), dim3(256), 0, stream,
                     ea, We, be, sc_all);
  hipLaunchKernelGGL(k_hist, dim3((N_EDGES + 255) / 256), dim3(256), 0, stream, ei, counts);
  hipLaunchKernelGGL(k_scan, dim3(1), dim3(1024), 0, stream, counts, roff);
  hipLaunchKernelGGL(k_scatter, dim3((N_EDGES + 255) / 256), dim3(256), 0, stream,
                     ei, roff, cursor, perm);
  hipLaunchKernelGGL(k_init, dim3(2048), dim3(256), 0, stream,
                     (const float4*)atom, (float4*)out, N_ATOMS * D / 4);
  hipLaunchKernelGGL(k_tile, dim3(N_EDGES / 64), dim3(256), 0, stream,
                     eap, ei, perm,
                     (const ushort_t*)PA, (const ushort_t*)PB,
                     (const ushort_t*)PGA, (const ushort_t*)PGB,
                     (const ushort_t*)WF, b2, g2, b3, g3, sc_all, out);
}

// Round 7
// 1269.403 us; speedup vs baseline: 29.4088x; 1.3481x over previous
//
#include <hip/hip_runtime.h>
#include <hip/hip_bf16.h>

#define N_ATOMS 100000
#define N_EDGES 1600000
#define D       128
#define DE      100
#define DSPH    9

typedef __hip_bfloat16 bf16;
typedef unsigned short ushort_t;
typedef short s16x8 __attribute__((ext_vector_type(8)));   // 8 bf16 (4 VGPR)
typedef float f32x4 __attribute__((ext_vector_type(4)));   // MFMA acc

#define MFMA16(a, b, c) __builtin_amdgcn_mfma_f32_16x16x32_bf16(a, b, c, 0, 0, 0)

__device__ __forceinline__ float blo(unsigned int u) {
  union { unsigned int i; float f; } v; v.i = u << 16; return v.f;
}
__device__ __forceinline__ float bhi(unsigned int u) {
  union { unsigned int i; float f; } v; v.i = u & 0xffff0000u; return v.f;
}
__device__ __forceinline__ unsigned short f2b(float x) {
  bf16 h = __float2bfloat16(x);
  return *(unsigned short*)&h;
}
__device__ __forceinline__ float fsig(float x) {
  return __builtin_amdgcn_rcpf(1.0f + __expf(-x));
}
__device__ __forceinline__ float fsilu(float x) { return x * fsig(x); }

// ---------------------------------------------------------------------------
// k_wprep: per-(tid,frag) bf16 B-operand fragments for k_tile (20 frags).
// ---------------------------------------------------------------------------
__global__ __launch_bounds__(256) void k_wprep(
    const float* __restrict__ W1, const float* __restrict__ b1,
    const float* __restrict__ W2, const float* __restrict__ W3,
    const float* __restrict__ G1, const float* __restrict__ g1v,
    const float* __restrict__ G2, const float* __restrict__ G3,
    ushort_t* __restrict__ WF)
{
  const int tid = threadIdx.x;
  const int lane = tid & 63, w = tid >> 6, fr = lane & 15, fg = lane >> 4;
  s16x8 fb[20];
#pragma unroll
  for (int q = 0; q < 2; ++q) {
    const int j = 16 * (2 * w + q) + fr;
    s16x8 bm, bg;
#pragma unroll
    for (int kk = 0; kk < 8; ++kk) {
      const int k = 8 * fg + kk;
      short vm = 0, vg = 0;
      if (k < 9)        { vm = (short)f2b(W1[(256 + k) * 128 + j]); vg = (short)f2b(G1[(256 + k) * 128 + j]); }
      else if (k == 31) { vm = (short)f2b(b1[j]);                    vg = (short)f2b(g1v[j]); }
      bm[kk] = vm; bg[kk] = vg;
    }
    fb[0 + q] = bm; fb[2 + q] = bg;
  }
  {
    const int j = 16 * w + fr;
#pragma unroll
    for (int ks = 0; ks < 4; ++ks) {
      s16x8 bm, bg;
#pragma unroll
      for (int kk = 0; kk < 8; ++kk) {
        const int k = 32 * ks + 8 * fg + kk;
        bm[kk] = (short)f2b(W2[k * 64 + j]);
        bg[kk] = (short)f2b(G2[k * 64 + j]);
      }
      fb[4 + ks] = bm; fb[8 + ks] = bg;
    }
  }
#pragma unroll
  for (int q = 0; q < 2; ++q) {
    const int j = 16 * (2 * w + q) + fr;
#pragma unroll
    for (int ks = 0; ks < 2; ++ks) {
      s16x8 bm, bg;
#pragma unroll
      for (int kk = 0; kk < 8; ++kk) {
        const int k = 32 * ks + 8 * fg + kk;
        bm[kk] = (short)f2b(W3[k * 128 + j]);
        bg[kk] = (short)f2b(G3[k * 128 + j]);
      }
      fb[12 + 2 * q + ks] = bm; fb[16 + 2 * q + ks] = bg;
    }
  }
#pragma unroll
  for (int f = 0; f < 20; ++f)
    ((s16x8*)WF)[f * 256 + tid] = fb[f];
}

// ---------------------------------------------------------------------------
// k_wprep2: B-fragments for k_tabmm.
// Wave w: side = w>>1 (0: src-half rows 0..127, 1: dst-half rows 128..255),
// jbase = 64*(w&1). cf slot 0..3 = main (W1), 4..7 = gate (G1).
// ---------------------------------------------------------------------------
__global__ __launch_bounds__(256) void k_wprep2(
    const float* __restrict__ W1, const float* __restrict__ G1,
    ushort_t* __restrict__ WF2)
{
  const int tid = threadIdx.x;
  const int lane = tid & 63, w = tid >> 6, fr = lane & 15, fg = lane >> 4;
  const int side = w >> 1, jbase = 64 * (w & 1);
  s16x8* WF2v = (s16x8*)WF2;
#pragma unroll
  for (int ks = 0; ks < 4; ++ks)
#pragma unroll
    for (int cf = 0; cf < 4; ++cf) {
      s16x8 bm, bg;
#pragma unroll
      for (int kk = 0; kk < 8; ++kk) {
        const int k = 32 * ks + 8 * fg + kk;
        const int j = jbase + 16 * cf + fr;
        const int row = side ? (128 + k) : k;
        bm[kk] = (short)f2b(W1[row * 128 + j]);
        bg[kk] = (short)f2b(G1[row * 128 + j]);
      }
      WF2v[((w * 4 + ks) * 8 + cf) * 64 + lane] = bm;
      WF2v[((w * 4 + ks) * 8 + cf + 4) * 64 + lane] = bg;
    }
}

// ---------------------------------------------------------------------------
// k_tabmm: MFMA GEMM [64 atoms x 128k] @ [128k x 512cols] -> packed tables.
// T_A[atom][j] = PA|PGA<<16, T_B[atom][j] = PB|PGB<<16 (bf16 pair in u32).
// Also writes out = atom_attr (residual base) while staging.
// ---------------------------------------------------------------------------
__global__ __launch_bounds__(256, 2) void k_tabmm(
    const float* __restrict__ atom, const ushort_t* __restrict__ WF2,
    unsigned* __restrict__ T_A, unsigned* __restrict__ T_B,
    float* __restrict__ out)
{
  __shared__ __align__(16) char ALDS[16384];   // 64 rows x 128 bf16 (swz16)
  const int tid = threadIdx.x;
  const int lane = tid & 63, w = tid >> 6, fr = lane & 15, fg = lane >> 4;
  const int abase = blockIdx.x * 64;

  // stage A (f32 -> bf16, XOR-swizzled) + residual copy to out.
  // R6 BUG FIX: full row is 32 float4s (128 floats), not 16 -> i < 2048, c4 = i&31.
  for (int i = tid; i < 2048; i += 256) {
    const int row = i >> 5, c4 = i & 31;
    const int a = abase + row;
    float4 v = make_float4(0.f, 0.f, 0.f, 0.f);
    if (a < N_ATOMS) {
      v = *(const float4*)(atom + (size_t)a * D + 4 * c4);
      *(float4*)(out + (size_t)a * D + 4 * c4) = v;
    }
    const unsigned lo = (unsigned)f2b(v.x) | ((unsigned)f2b(v.y) << 16);
    const unsigned hi = (unsigned)f2b(v.z) | ((unsigned)f2b(v.w) << 16);
    const int byte = row * 256 + ((8 * c4) ^ ((row & 15) << 4));
    *(uint2*)(ALDS + byte) = make_uint2(lo, hi);
  }
  __syncthreads();

  f32x4 am[4][4], ag[4][4];
#pragma unroll
  for (int rf = 0; rf < 4; ++rf)
#pragma unroll
    for (int cf = 0; cf < 4; ++cf) {
      am[rf][cf] = (f32x4){0.f, 0.f, 0.f, 0.f};
      ag[rf][cf] = (f32x4){0.f, 0.f, 0.f, 0.f};
    }

  const s16x8* WF2v = (const s16x8*)WF2;
#pragma unroll
  for (int ks = 0; ks < 4; ++ks) {
    s16x8 a[4];
#pragma unroll
    for (int rf = 0; rf < 4; ++rf) {
      const int row = 16 * rf + fr;
      a[rf] = *(const s16x8*)(ALDS + row * 256 + ((64 * ks + 16 * fg) ^ (fr << 4)));
    }
#pragma unroll
    for (int cf = 0; cf < 4; ++cf) {
      const s16x8 Bm = WF2v[((w * 4 + ks) * 8 + cf) * 64 + lane];
      const s16x8 Bg = WF2v[((w * 4 + ks) * 8 + cf + 4) * 64 + lane];
#pragma unroll
      for (int rf = 0; rf < 4; ++rf) {
        am[rf][cf] = MFMA16(a[rf], Bm, am[rf][cf]);
        ag[rf][cf] = MFMA16(a[rf], Bg, ag[rf][cf]);
      }
    }
  }

  const int side = w >> 1, jbase = 64 * (w & 1);
  unsigned* T = side ? T_B : T_A;
#pragma unroll
  for (int rf = 0; rf < 4; ++rf)
#pragma unroll
    for (int cf = 0; cf < 4; ++cf)
#pragma unroll
      for (int r = 0; r < 4; ++r) {
        const int a = abase + 16 * rf + 4 * fg + r;
        if (a < N_ATOMS) {
          const unsigned u = (unsigned)f2b(am[rf][cf][r]) |
                             ((unsigned)f2b(ag[rf][cf][r]) << 16);
          T[(size_t)a * D + jbase + 16 * cf + fr] = u;
        }
      }
}

// ---------------------------------------------------------------------------
// k_sc_hist: sc[e] = ea[e,:]@We + be (8 lanes/edge) + dst histogram.
// ---------------------------------------------------------------------------
__global__ __launch_bounds__(256) void k_sc_hist(const float* __restrict__ ea,
                                                 const float* __restrict__ We,
                                                 const float* __restrict__ be,
                                                 const int* __restrict__ ei,
                                                 float* __restrict__ sc,
                                                 int* __restrict__ counts) {
  const int tid = threadIdx.x;
  const int r = tid & 7;
  const long e = (long)blockIdx.x * 32 + (tid >> 3);
  const float4* row = (const float4*)(ea + e * DE);
  const float4* Wv = (const float4*)We;
  const float4 w0 = Wv[r], w1 = Wv[r + 8], w2 = Wv[r + 16];
  const float4 d0 = row[r], d1 = row[r + 8], d2 = row[r + 16];
  float s = d0.x * w0.x;
  s = fmaf(d0.y, w0.y, s); s = fmaf(d0.z, w0.z, s); s = fmaf(d0.w, w0.w, s);
  s = fmaf(d1.x, w1.x, s); s = fmaf(d1.y, w1.y, s); s = fmaf(d1.z, w1.z, s);
  s = fmaf(d1.w, w1.w, s); s = fmaf(d2.x, w2.x, s); s = fmaf(d2.y, w2.y, s);
  s = fmaf(d2.z, w2.z, s); s = fmaf(d2.w, w2.w, s);
  if (r == 0) {
    const float4 w3 = Wv[24], d3 = row[24];
    s = fmaf(d3.x, w3.x, s); s = fmaf(d3.y, w3.y, s);
    s = fmaf(d3.z, w3.z, s); s = fmaf(d3.w, w3.w, s);
  }
  s += __shfl_xor(s, 1); s += __shfl_xor(s, 2); s += __shfl_xor(s, 4);
  if (r == 0) {
    sc[e] = s + be[0];
    atomicAdd(&counts[ei[N_EDGES + e]], 1);
  }
}

// ---------------------------------------------------------------------------
// CSR: scan + scatter
// ---------------------------------------------------------------------------
__global__ __launch_bounds__(1024) void k_scan(const int* __restrict__ counts,
                                               int* __restrict__ roff) {
  __shared__ int ssum[1024];
  const int tid = threadIdx.x;
  const int CH = (N_ATOMS + 1023) / 1024;
  const int base = tid * CH;
  int s = 0;
  for (int k = 0; k < CH; ++k) {
    int idx = base + k;
    if (idx < N_ATOMS) s += counts[idx];
  }
  ssum[tid] = s;
  __syncthreads();
  for (int off = 1; off < 1024; off <<= 1) {
    int v = 0;
    if (tid >= off) v = ssum[tid - off];
    __syncthreads();
    if (tid >= off) ssum[tid] += v;
    __syncthreads();
  }
  s = (tid == 0) ? 0 : ssum[tid - 1];
  for (int k = 0; k < CH; ++k) {
    int idx = base + k;
    if (idx < N_ATOMS) { roff[idx] = s; s += counts[idx]; }
  }
  if (tid == 1023) roff[N_ATOMS] = s;
}

__global__ __launch_bounds__(256) void k_scatter(const int* __restrict__ ei,
                                                 const int* __restrict__ roff,
                                                 int* __restrict__ cursor,
                                                 int* __restrict__ perm) {
  int e = blockIdx.x * 256 + threadIdx.x;
  if (e < N_EDGES) {
    int d = ei[N_EDGES + e];
    int p = atomicAdd(&cursor[d], 1);
    perm[roff[d] + p] = e;
  }
}

// ---------------------------------------------------------------------------
// k_tile: 64 dst-sorted edges per block, 256 thr (4 waves), 3 blocks/CU.
// LDS overlay (50176 B):
//   X [0,32K):  H1M/H1G (L1..L2) -> MSG (L3 epi..reduce)
//   Y [32K,48K): sph [32K,36K) (ph1..L1) -> H2M/H2G [32K,48K) (L2 epi..L3)
//   tails [48K,50K): dst, sc, src, e
// ---------------------------------------------------------------------------
#define OFF_H1M 0
#define OFF_H1G 16384
#define OFF_MSG 0
#define OFF_SPH 32768
#define OFF_H2M 32768
#define OFF_H2G 40960
#define OFF_DST 49152
#define OFF_SC  49408
#define OFF_SRC 49664
#define OFF_E   49920

__global__ __launch_bounds__(256, 3) void k_tile(
    const float* __restrict__ eap,
    const int*  __restrict__ ei, const int* __restrict__ perm,
    const unsigned* __restrict__ T_A, const unsigned* __restrict__ T_B,
    const ushort_t* __restrict__ WF,
    const float* __restrict__ b2v, const float* __restrict__ g2v,
    const float* __restrict__ b3v, const float* __restrict__ g3v,
    const float* __restrict__ sc_all,
    float* __restrict__ out)
{
  __shared__ __align__(16) char BUF[50176];
  const int tid  = threadIdx.x;
  const int lane = tid & 63;
  const int w    = tid >> 6;        // wave 0..3
  const int fr   = lane & 15;       // frag row
  const int fg   = lane >> 4;       // frag k-group / C row-group
  const long E0  = (long)blockIdx.x * 64;

  int*   e_s   = (int*)(BUF + OFF_E);
  int*   src_s = (int*)(BUF + OFF_SRC);
  int*   dst_s = (int*)(BUF + OFF_DST);
  float* sc_s  = (float*)(BUF + OFF_SC);

  // ---- phase 1: edge indices + scalar + sph pad (k>=10; k31 = 1.0 bias) ----
  if (tid < 64) {
    const int e = perm[E0 + tid];
    e_s[tid]   = e;
    src_s[tid] = ei[e];
    dst_s[tid] = ei[N_EDGES + e];
    sc_s[tid]  = sc_all[e];
  }
  for (int idx = tid; idx < 64 * 11; idx += 256) {
    const int i = idx / 11, ww = 5 + idx % 11;
    ((unsigned int*)(BUF + OFF_SPH))[i * 16 + ww] = (ww == 15) ? 0x3F800000u : 0u;
  }

  // ---- prologue: weight fragments (precomputed, coalesced dwordx4) ----
  const s16x8* WFv = (const s16x8*)WF;
  s16x8 B1m[2], B1g[2], B2m[4], B2g[4], B3m[2][2], B3g[2][2];
#pragma unroll
  for (int q = 0; q < 2; ++q) { B1m[q] = WFv[(0 + q) * 256 + tid]; B1g[q] = WFv[(2 + q) * 256 + tid]; }
#pragma unroll
  for (int ks = 0; ks < 4; ++ks) { B2m[ks] = WFv[(4 + ks) * 256 + tid]; B2g[ks] = WFv[(8 + ks) * 256 + tid]; }
#pragma unroll
  for (int q = 0; q < 2; ++q)
#pragma unroll
    for (int ks = 0; ks < 2; ++ks) {
      B3m[q][ks] = WFv[(12 + 2 * q + ks) * 256 + tid];
      B3g[q][ks] = WFv[(16 + 2 * q + ks) * 256 + tid];
    }
  const float b2j = b2v[16 * w + fr], g2j = g2v[16 * w + fr];
  const float b3j0 = b3v[16 * 2 * w + fr],       g3j0 = g3v[16 * 2 * w + fr];
  const float b3j1 = b3v[16 * (2 * w + 1) + fr], g3j1 = g3v[16 * (2 * w + 1) + fr];
  __syncthreads();   // bar A: e_s/src/dst/sc + sph pad visible

  // ---- phase 2: sph fill (k<10) ----
  for (int idx = tid; idx < 640; idx += 256) {
    const int i = idx / 10, k = idx % 10;
    unsigned short v = 0;
    if (k < 9) v = f2b(eap[(size_t)e_s[i] * DSPH + k]);
    *(unsigned short*)(BUF + OFF_SPH + i * 64 + k * 2) = v;
  }
  __syncthreads();   // bar B: sph visible

  // ---- L1: Z1 = sph @ W1cT(+bias); epi gathers T_A/T_B, silu -> H1 ----
  f32x4 a1m[4][2], a1g[4][2];
#pragma unroll
  for (int me = 0; me < 4; ++me)
#pragma unroll
    for (int q = 0; q < 2; ++q) { a1m[me][q] = (f32x4){0.f,0.f,0.f,0.f}; a1g[me][q] = (f32x4){0.f,0.f,0.f,0.f}; }
#pragma unroll
  for (int me = 0; me < 4; ++me) {
    const s16x8 a = *(const s16x8*)(BUF + OFF_SPH + (16 * me + fr) * 64 + fg * 16);
#pragma unroll
    for (int q = 0; q < 2; ++q) {
      a1m[me][q] = MFMA16(a, B1m[q], a1m[me][q]);
      a1g[me][q] = MFMA16(a, B1g[q], a1g[me][q]);
    }
  }
#pragma unroll
  for (int me = 0; me < 4; ++me)
#pragma unroll
    for (int q = 0; q < 2; ++q) {
      const int col = 16 * (2 * w + q) + fr;
#pragma unroll
      for (int r = 0; r < 4; ++r) {
        const int e = 16 * me + 4 * fg + r;
        const unsigned va = T_A[(size_t)src_s[e] * D + col];
        const unsigned vb = T_B[(size_t)dst_s[e] * D + col];
        const float zm = a1m[me][q][r] + blo(va) + blo(vb);
        const float zg = a1g[me][q][r] + bhi(va) + bhi(vb);
        const int cb = (col * 2) ^ ((e & 15) << 4);
        *(unsigned short*)(BUF + OFF_H1M + e * 256 + cb) = f2b(fsilu(zm));
        *(unsigned short*)(BUF + OFF_H1G + e * 256 + cb) = f2b(fsilu(zg));
      }
    }
  __syncthreads();   // bar C: H1 ready

  // ---- L2: Z2 = H1 @ W2 (+b2) ; silu -> H2 (Y region) ----
  f32x4 a2m[4], a2g[4];
#pragma unroll
  for (int me = 0; me < 4; ++me) { a2m[me] = (f32x4){b2j,b2j,b2j,b2j}; a2g[me] = (f32x4){g2j,g2j,g2j,g2j}; }
#pragma unroll
  for (int me = 0; me < 4; ++me) {
    const int row = 16 * me + fr;
#pragma unroll
    for (int ks = 0; ks < 4; ++ks) {
      const int cb = (64 * ks + 16 * fg) ^ ((row & 15) << 4);
      const s16x8 am = *(const s16x8*)(BUF + OFF_H1M + row * 256 + cb);
      const s16x8 ag = *(const s16x8*)(BUF + OFF_H1G + row * 256 + cb);
      a2m[me] = MFMA16(am, B2m[ks], a2m[me]);
      a2g[me] = MFMA16(ag, B2g[ks], a2g[me]);
    }
  }
  {
    const int j2 = 16 * w + fr;
#pragma unroll
    for (int me = 0; me < 4; ++me)
#pragma unroll
      for (int r = 0; r < 4; ++r) {
        const int e = 16 * me + 4 * fg + r;
        const int cb = (j2 * 2) ^ ((e & 7) << 4);
        *(unsigned short*)(BUF + OFF_H2M + e * 128 + cb) = f2b(fsilu(a2m[me][r]));
        *(unsigned short*)(BUF + OFF_H2G + e * 128 + cb) = f2b(fsilu(a2g[me][r]));
      }
  }
  __syncthreads();   // bar D: H2 ready (and all H1 reads done)

  // ---- L3: Z3 = H2 @ W3 (+b3) ; msg -> MSG (X region, overlays H1) ----
  f32x4 a3m[4][2], a3g[4][2];
#pragma unroll
  for (int me = 0; me < 4; ++me) {
    a3m[me][0] = (f32x4){b3j0,b3j0,b3j0,b3j0}; a3g[me][0] = (f32x4){g3j0,g3j0,g3j0,g3j0};
    a3m[me][1] = (f32x4){b3j1,b3j1,b3j1,b3j1}; a3g[me][1] = (f32x4){g3j1,g3j1,g3j1,g3j1};
  }
#pragma unroll
  for (int me = 0; me < 4; ++me) {
    const int row = 16 * me + fr;
#pragma unroll
    for (int ks = 0; ks < 2; ++ks) {
      const int cb = (64 * ks + 16 * fg) ^ ((row & 7) << 4);
      const s16x8 am = *(const s16x8*)(BUF + OFF_H2M + row * 128 + cb);
      const s16x8 ag = *(const s16x8*)(BUF + OFF_H2G + row * 128 + cb);
#pragma unroll
      for (int q = 0; q < 2; ++q) {
        a3m[me][q] = MFMA16(am, B3m[q][ks], a3m[me][q]);
        a3g[me][q] = MFMA16(ag, B3g[q][ks], a3g[me][q]);
      }
    }
  }
#pragma unroll
  for (int me = 0; me < 4; ++me)
#pragma unroll
    for (int q = 0; q < 2; ++q) {
      const int col = 16 * (2 * w + q) + fr;
#pragma unroll
      for (int r = 0; r < 4; ++r) {
        const int e = 16 * me + 4 * fg + r;
        const float msg = fsilu(a3m[me][q][r]) * fsig(a3g[me][q][r]) * sc_s[e];
        *(float*)(BUF + OFF_MSG + (e * 128 + col) * 4) = msg;
      }
    }
  __syncthreads();   // bar E: MSG ready

  // ---- segmented reduce: col-pair x edge-quarter (16-long chains) ----
  {
    const int cp = tid & 63;          // cols 2cp, 2cp+1
    const int qt = tid >> 6;          // quarter 0..3 (wave-uniform)
    const int base = 16 * qt;
    int cur = dst_s[base];
    float2 acc = *(const float2*)(BUF + OFF_MSG + (base * 128 + 2 * cp) * 4);
    for (int e2 = 1; e2 < 16; ++e2) {
      const int d = dst_s[base + e2];
      const float2 v = *(const float2*)(BUF + OFF_MSG + ((base + e2) * 128 + 2 * cp) * 4);
      if (d != cur) {
        atomicAdd(out + (size_t)cur * D + 2 * cp,     acc.x);
        atomicAdd(out + (size_t)cur * D + 2 * cp + 1, acc.y);
        cur = d; acc = v;
      } else { acc.x += v.x; acc.y += v.y; }
    }
    atomicAdd(out + (size_t)cur * D + 2 * cp,     acc.x);
    atomicAdd(out + (size_t)cur * D + 2 * cp + 1, acc.y);
  }
}

// ---------------------------------------------------------------------------
extern "C" void kernel_launch(void* const* d_in, const int* in_sizes, int n_in,
                              void* d_out, int out_size, void* d_ws, size_t ws_size,
                              hipStream_t stream) {
  const float* atom = (const float*)d_in[0];
  const float* ea   = (const float*)d_in[1];
  const float* eap  = (const float*)d_in[2];
  const int*   ei   = (const int*)d_in[3];
  const float* W1 = (const float*)d_in[5];
  const float* b1 = (const float*)d_in[6];
  const float* W2 = (const float*)d_in[7];
  const float* b2 = (const float*)d_in[8];
  const float* W3 = (const float*)d_in[9];
  const float* b3 = (const float*)d_in[10];
  const float* G1 = (const float*)d_in[11];
  const float* g1 = (const float*)d_in[12];
  const float* G2 = (const float*)d_in[13];
  const float* g2 = (const float*)d_in[14];
  const float* G3 = (const float*)d_in[15];
  const float* g3 = (const float*)d_in[16];
  const float* We = (const float*)d_in[17];
  const float* be = (const float*)d_in[18];
  float* out = (float*)d_out;

  char* wp = (char*)d_ws;
  unsigned* T_A = (unsigned*)wp;            wp += (size_t)N_ATOMS * D * 4;
  unsigned* T_B = (unsigned*)wp;            wp += (size_t)N_ATOMS * D * 4;
  int* counts = (int*)wp;                   wp += (size_t)N_ATOMS * 4;
  int* roff   = (int*)wp;                   wp += (size_t)(N_ATOMS + 4) * 4;
  int* cursor = (int*)wp;                   wp += (size_t)N_ATOMS * 4;
  int* perm   = (int*)wp;                   wp += (size_t)N_EDGES * 4;
  ushort_t* WF  = (ushort_t*)wp;            wp += (size_t)20 * 256 * 8 * 2;
  ushort_t* WF2 = (ushort_t*)wp;            wp += (size_t)4 * 4 * 8 * 64 * 8 * 2;
  float* sc_all = (float*)wp;               wp += (size_t)N_EDGES * 4;

  hipMemsetAsync(counts, 0, (size_t)N_ATOMS * 4, stream);
  hipMemsetAsync(cursor, 0, (size_t)N_ATOMS * 4, stream);

  hipLaunchKernelGGL(k_wprep, dim3(1), dim3(256), 0, stream,
                     W1, b1, W2, W3, G1, g1, G2, G3, WF);
  hipLaunchKernelGGL(k_wprep2, dim3(1), dim3(256), 0, stream, W1, G1, WF2);
  hipLaunchKernelGGL(k_sc_hist, dim3(N_EDGES / 32), dim3(256), 0, stream,
                     ea, We, be, ei, sc_all, counts);
  hipLaunchKernelGGL(k_scan, dim3(1), dim3(1024), 0, stream, counts, roff);
  hipLaunchKernelGGL(k_scatter, dim3((N_EDGES + 255) / 256), dim3(256), 0, stream,
                     ei, roff, cursor, perm);
  hipLaunchKernelGGL(k_tabmm, dim3((N_ATOMS + 63) / 64), dim3(256), 0, stream,
                     atom, WF2, T_A, T_B, out);
  hipLaunchKernelGGL(k_tile, dim3(N_EDGES / 64), dim3(256), 0, stream,
                     eap, ei, perm, T_A, T_B, WF, b2, g2, b3, g3, sc_all, out);
}